// Round 1
// baseline (3819.986 us; speedup 1.0000x reference)
//
#include <hip/hip_runtime.h>

typedef __attribute__((ext_vector_type(4))) float f4;
typedef __attribute__((ext_vector_type(8))) short s8v;
typedef __attribute__((ext_vector_type(4))) short s4v;
typedef __attribute__((ext_vector_type(4))) unsigned short u4v;

__device__ __forceinline__ short f2bf(float f) {
  union { float f; unsigned int u; } v; v.f = f;
  unsigned int u = v.u;
  unsigned int r = 0x7fffu + ((u >> 16) & 1u);
  return (short)((u + r) >> 16);
}

#define LDSLD 40  // shorts per LDS row (32 data + 8 pad) -> 80B stride, 16B-aligned

// Stage a 128x32 tile from a row-major (rows, K) source into LDS [r][k].
__device__ __forceinline__ void stage_rows_f32(short* dst, const float* src, int ld,
                                               int row0, int k0, int tid) {
  int r = tid >> 3;
  int kq = (tid & 7) * 4;
#pragma unroll
  for (int p = 0; p < 4; ++p) {
    int rr = p * 32 + r;
    const float* s = src + (size_t)(row0 + rr) * ld + (k0 + kq);
    f4 f = *(const f4*)s;
    s4v v;
    v[0] = f2bf(f[0]); v[1] = f2bf(f[1]); v[2] = f2bf(f[2]); v[3] = f2bf(f[3]);
    *(s4v*)&dst[rr * LDSLD + kq] = v;
  }
}

__device__ __forceinline__ void stage_rows_bf16(short* dst, const unsigned short* src, int ld,
                                                int row0, int k0, int tid) {
  int r = tid >> 3;
  int kq = (tid & 7) * 4;
#pragma unroll
  for (int p = 0; p < 4; ++p) {
    int rr = p * 32 + r;
    const unsigned short* s = src + (size_t)(row0 + rr) * ld + (k0 + kq);
    u4v u = *(const u4v*)s;
    s4v v;
    v[0] = (short)u[0]; v[1] = (short)u[1]; v[2] = (short)u[2]; v[3] = (short)u[3];
    *(s4v*)&dst[rr * LDSLD + kq] = v;
  }
}

// Stage a 32x128 tile from a row-major (K, N) source, transposed into LDS [n][k].
__device__ __forceinline__ void stage_cols_f32(short* dst, const float* src, int ld,
                                               int n0, int k0, int tid) {
  int n = tid & 127;
  int kh = (tid >> 7) * 16;
  const float* s = src + (size_t)(k0 + kh) * ld + (n0 + n);
  short tmp[16];
#pragma unroll
  for (int j = 0; j < 16; ++j) tmp[j] = f2bf(s[(size_t)j * ld]);
  s8v v0, v1;
#pragma unroll
  for (int j = 0; j < 8; ++j) { v0[j] = tmp[j]; v1[j] = tmp[8 + j]; }
  *(s8v*)&dst[n * LDSLD + kh] = v0;
  *(s8v*)&dst[n * LDSLD + kh + 8] = v1;
}

// C = op(A @ B + bias) (+ res). A: (M,K) f32 or bf16. B: (K,N) f32, or BTRANS: (N,K) f32.
// 128x128 tile, BK=32, 256 threads = 4 waves of 64x64.
template<int ABF16, int BTRANS, int BIAS, int RES, int RELU>
__global__ __launch_bounds__(256) void gemm_k(
    const void* __restrict__ Av, const float* __restrict__ Bm,
    const float* __restrict__ bias, const float* __restrict__ res,
    float* __restrict__ C,
    int M, int N, int K, int lda, int ldb, int ldc, int ldr,
    long sA, long sB, long sC, long sR) {
  __shared__ short Alds[128 * LDSLD];
  __shared__ short Blds[128 * LDSLD];
  int tid = threadIdx.x;
  int bz = blockIdx.z;
  const float* Af = nullptr;
  const unsigned short* Ah = nullptr;
  if (ABF16) Ah = (const unsigned short*)Av + (size_t)bz * sA;
  else       Af = (const float*)Av + (size_t)bz * sA;
  const float* Bp = Bm + (size_t)bz * sB;
  float* Cp = C + (size_t)bz * sC;
  const float* Rp = RES ? (res + (size_t)bz * sR) : nullptr;
  int bn0 = blockIdx.x * 128;
  int bm0 = blockIdx.y * 128;
  int lane = tid & 63, wid = tid >> 6;
  int wm = (wid >> 1) * 64, wn = (wid & 1) * 64;
  f4 acc[4][4] = {};
  int nk = K >> 5;
  for (int kt = 0; kt < nk; ++kt) {
    int k0 = kt << 5;
    __syncthreads();
    if (ABF16) stage_rows_bf16(Alds, Ah, lda, bm0, k0, tid);
    else       stage_rows_f32(Alds, Af, lda, bm0, k0, tid);
    if (BTRANS) stage_rows_f32(Blds, Bp, ldb, bn0, k0, tid);
    else        stage_cols_f32(Blds, Bp, ldb, bn0, k0, tid);
    __syncthreads();
    const short* Ab = &Alds[(wm + (lane & 15)) * LDSLD + (lane >> 4) * 8];
    const short* Bb = &Blds[(wn + (lane & 15)) * LDSLD + (lane >> 4) * 8];
    s8v a[4], b[4];
#pragma unroll
    for (int i = 0; i < 4; ++i) a[i] = *(const s8v*)(Ab + i * 16 * LDSLD);
#pragma unroll
    for (int j = 0; j < 4; ++j) b[j] = *(const s8v*)(Bb + j * 16 * LDSLD);
#pragma unroll
    for (int i = 0; i < 4; ++i)
#pragma unroll
      for (int j = 0; j < 4; ++j)
        acc[i][j] = __builtin_amdgcn_mfma_f32_16x16x32_bf16(a[i], b[j], acc[i][j], 0, 0, 0);
  }
#pragma unroll
  for (int i = 0; i < 4; ++i) {
#pragma unroll
    for (int j = 0; j < 4; ++j) {
#pragma unroll
      for (int r = 0; r < 4; ++r) {
        int row = bm0 + wm + i * 16 + (lane >> 4) * 4 + r;
        int col = bn0 + wn + j * 16 + (lane & 15);
        float v = acc[i][j][r];
        if (BIAS) v += bias[col];
        if (RELU) v = fmaxf(v, 0.f);
        if (RES) v += Rp[(size_t)row * ldr + col];
        Cp[(size_t)row * ldc + col] = v;
      }
    }
  }
}

__device__ __forceinline__ float wave_max(float v) {
#pragma unroll
  for (int off = 32; off > 0; off >>= 1) v = fmaxf(v, __shfl_xor(v, off));
  return v;
}
__device__ __forceinline__ float wave_sum(float v) {
#pragma unroll
  for (int off = 32; off > 0; off >>= 1) v += __shfl_xor(v, off);
  return v;
}

// Row softmax over 512 cols with scale (+ causal mask); writes f32 back in place and bf16 copy.
template<int CAUSAL>
__global__ __launch_bounds__(256) void softmax_k(float* __restrict__ Sm,
                                                 unsigned short* __restrict__ Wb) {
  int row = blockIdx.x;  // b*512 + q
  int q = row & 511;
  int t = threadIdx.x;
  float* Sp = Sm + (size_t)row * 512;
  const float scale = 0.03125f;
  float v0 = Sp[t] * scale;
  float v1 = Sp[t + 256] * scale;
  if (CAUSAL) {
    if (t > q) v0 = -1.0e7f;
    if (t + 256 > q) v1 = -1.0e7f;
  }
  __shared__ float red[4], red2[4];
  int lane = t & 63, wid = t >> 6;
  float m = wave_max(fmaxf(v0, v1));
  if (lane == 0) red[wid] = m;
  __syncthreads();
  m = fmaxf(fmaxf(red[0], red[1]), fmaxf(red[2], red[3]));
  float e0 = __expf(v0 - m);
  float e1 = __expf(v1 - m);
  float s = wave_sum(e0 + e1);
  if (lane == 0) red2[wid] = s;
  __syncthreads();
  s = (red2[0] + red2[1]) + (red2[2] + red2[3]);
  float inv = 1.0f / s;
  float w0 = e0 * inv, w1 = e1 * inv;
  Sp[t] = w0;
  Sp[t + 256] = w1;
  unsigned short* wp = Wb + (size_t)row * 512;
  wp[t] = (unsigned short)f2bf(w0);
  wp[t + 256] = (unsigned short)f2bf(w1);
}

// out[b,k,q] = S[b,q,k]  (512x512 per batch), 64x64 LDS tiles.
__global__ __launch_bounds__(256) void transpose_k(const float* __restrict__ Sm,
                                                   float* __restrict__ out) {
  __shared__ float tile[64][65];
  int b = blockIdx.z;
  int q0 = blockIdx.x * 64, k0 = blockIdx.y * 64;
  const float* Sp = Sm + (size_t)b * 512 * 512;
  float* op = out + (size_t)b * 512 * 512;
  int tx = threadIdx.x & 63, ty = threadIdx.x >> 6;
#pragma unroll
  for (int j = 0; j < 16; ++j) {
    int qq = j * 4 + ty;
    tile[qq][tx] = Sp[(size_t)(q0 + qq) * 512 + k0 + tx];
  }
  __syncthreads();
#pragma unroll
  for (int j = 0; j < 16; ++j) {
    int kk = j * 4 + ty;
    op[(size_t)(k0 + kk) * 512 + q0 + tx] = tile[tx][kk];
  }
}

// contexts[b,s,:] = embedding[ids[b,s],:] + pe(s,:)
__global__ __launch_bounds__(256) void embed_pe_k(const int* __restrict__ ids,
                                                  const float* __restrict__ emb,
                                                  float* __restrict__ ctx) {
  int row = blockIdx.x;  // b*512 + s
  int s = row & 511;
  int t = threadIdx.x;
  int id = ids[row];
  f4 e = *(const f4*)(emb + (size_t)id * 1024 + t * 4);
  int j0 = 2 * t, j1 = 2 * t + 1;
  float fr0 = powf(10000.0f, -2.0f * (float)j0 / 1024.0f);
  float fr1 = powf(10000.0f, -2.0f * (float)j1 / 1024.0f);
  float s0, c0, s1, c1;
  sincosf((float)s * fr0, &s0, &c0);
  sincosf((float)s * fr1, &s1, &c1);
  f4 o;
  o[0] = e[0] + s0;
  o[1] = e[1] + c0;
  o[2] = e[2] + s1;
  o[3] = e[3] + c1;
  *(f4*)(ctx + (size_t)row * 1024 + t * 4) = o;
}

extern "C" void kernel_launch(void* const* d_in, const int* in_sizes, int n_in,
                              void* d_out, int out_size, void* d_ws, size_t ws_size,
                              hipStream_t stream) {
  const int B = 8, S = 512, H = 1024, V = 32000, L = 6;
  const int M = B * S;  // 4096

  const int* ids = (const int*)d_in[0];
  const float* ann = (const float*)d_in[1];
  const float* emb = (const float*)d_in[3];
  const float* Wq_s = (const float*)d_in[4];
  const float* bq_s = (const float*)d_in[5];
  const float* Wk_s = (const float*)d_in[6];
  const float* bk_s = (const float*)d_in[7];
  const float* Wv_s = (const float*)d_in[8];
  const float* bv_s = (const float*)d_in[9];
  const float* Wq_c = (const float*)d_in[10];
  const float* bq_c = (const float*)d_in[11];
  const float* Wk_c = (const float*)d_in[12];
  const float* bk_c = (const float*)d_in[13];
  const float* Wv_c = (const float*)d_in[14];
  const float* bv_c = (const float*)d_in[15];
  const float* Wm = (const float*)d_in[16];
  const float* bm = (const float*)d_in[17];
  const float* Wout = (const float*)d_in[18];
  const float* bout = (const float*)d_in[19];
  float* out = (float*)d_out;

  char* ws = (char*)d_ws;
  if (ws_size < ((size_t)92 << 20)) return;
  float* X0 = (float*)ws;                              // 16MB contexts ping
  float* X1 = (float*)(ws + ((size_t)16 << 20));       // 16MB contexts pong
  float* Qb = (float*)(ws + ((size_t)32 << 20));       // 16MB
  float* Kb = (float*)(ws + ((size_t)48 << 20));       // 16MB
  float* Vb = (float*)(ws + ((size_t)64 << 20));       // 16MB
  float* Sb = (float*)(ws + ((size_t)80 << 20));       // 8MB scores
  unsigned short* Wp = (unsigned short*)(ws + ((size_t)88 << 20));  // 4MB bf16 weights

  size_t enc_off = (size_t)M * V;                      // 131,072,000
  size_t self_off = enc_off + (size_t)L * B * S * S;   // + 12,582,912

  embed_pe_k<<<M, 256, 0, stream>>>(ids, emb, X0);

  float* P = X0;
  float* Palt = X1;
  long sQ = (long)S * H;    // per-batch stride of (B,512,1024)
  long sS = (long)S * S;

  for (int l = 0; l < L; ++l) {
    size_t wo = (size_t)l * H * H;
    size_t bo = (size_t)l * H;
    // ---- self attention ----
    gemm_k<0, 0, 1, 0, 0><<<dim3(H / 128, M / 128, 1), 256, 0, stream>>>(
        P, Wq_s + wo, bq_s + bo, nullptr, Qb, M, H, H, H, H, H, 0, 0, 0, 0, 0);
    gemm_k<0, 0, 1, 0, 0><<<dim3(H / 128, M / 128, 1), 256, 0, stream>>>(
        P, Wk_s + wo, bk_s + bo, nullptr, Kb, M, H, H, H, H, H, 0, 0, 0, 0, 0);
    gemm_k<0, 0, 1, 0, 0><<<dim3(H / 128, M / 128, 1), 256, 0, stream>>>(
        P, Wv_s + wo, bv_s + bo, nullptr, Vb, M, H, H, H, H, H, 0, 0, 0, 0, 0);
    // scores[b] = Q[b] @ K[b]^T   (batched)
    gemm_k<0, 1, 0, 0, 0><<<dim3(S / 128, S / 128, B), 256, 0, stream>>>(
        Qb, Kb, nullptr, nullptr, Sb, S, S, H, H, H, S, 0, sQ, sQ, sS, 0);
    softmax_k<1><<<B * S, 256, 0, stream>>>(Sb, Wp);
    transpose_k<<<dim3(8, 8, B), 256, 0, stream>>>(Sb, out + self_off + (size_t)l * B * S * S);
    // R1 = P + W @ V   (batched, A bf16)
    gemm_k<1, 0, 0, 1, 0><<<dim3(H / 128, S / 128, B), 256, 0, stream>>>(
        Wp, Vb, nullptr, P, Palt, S, H, S, S, H, H, H, sS, sQ, sQ, sQ);
    // ---- cross attention ----
    gemm_k<0, 0, 1, 0, 0><<<dim3(H / 128, M / 128, 1), 256, 0, stream>>>(
        Palt, Wq_c + wo, bq_c + bo, nullptr, Qb, M, H, H, H, H, H, 0, 0, 0, 0, 0);
    gemm_k<0, 0, 1, 0, 0><<<dim3(H / 128, M / 128, 1), 256, 0, stream>>>(
        ann, Wk_c + wo, bk_c + bo, nullptr, Kb, M, H, H, H, H, H, 0, 0, 0, 0, 0);
    gemm_k<0, 0, 1, 0, 0><<<dim3(H / 128, M / 128, 1), 256, 0, stream>>>(
        ann, Wv_c + wo, bv_c + bo, nullptr, Vb, M, H, H, H, H, H, 0, 0, 0, 0, 0);
    gemm_k<0, 1, 0, 0, 0><<<dim3(S / 128, S / 128, B), 256, 0, stream>>>(
        Qb, Kb, nullptr, nullptr, Sb, S, S, H, H, H, S, 0, sQ, sQ, sS, 0);
    softmax_k<0><<<B * S, 256, 0, stream>>>(Sb, Wp);
    transpose_k<<<dim3(8, 8, B), 256, 0, stream>>>(Sb, out + enc_off + (size_t)l * B * S * S);
    // R2 = R1 + W @ V  -> written into P's buffer
    gemm_k<1, 0, 0, 1, 0><<<dim3(H / 128, S / 128, B), 256, 0, stream>>>(
        Wp, Vb, nullptr, Palt, P, S, H, S, S, H, H, H, sS, sQ, sQ, sQ);
    // contexts' = R2 + relu(R2 @ Wm + bm) -> written into Palt
    gemm_k<0, 0, 1, 1, 1><<<dim3(H / 128, M / 128, 1), 256, 0, stream>>>(
        P, Wm + wo, bm + bo, P, Palt, M, H, H, H, H, H, H, 0, 0, 0, 0);
    float* t = P; P = Palt; Palt = t;
  }

  // logits = contexts @ Wout + bout
  gemm_k<0, 0, 1, 0, 0><<<dim3(V / 128, M / 128, 1), 256, 0, stream>>>(
      P, Wout, bout, nullptr, out, M, V, H, H, V, V, 0, 0, 0, 0, 0);
}

// Round 2
// 2188.354 us; speedup vs baseline: 1.7456x; 1.7456x over previous
//
#include <hip/hip_runtime.h>

typedef __attribute__((ext_vector_type(4))) float f4;
typedef __attribute__((ext_vector_type(8))) short s8v;
typedef __attribute__((ext_vector_type(4))) short s4v;

__device__ __forceinline__ short f2bf(float f) {
  union { float f; unsigned int u; } v; v.f = f;
  unsigned int u = v.u;
  unsigned int r = 0x7fffu + ((u >> 16) & 1u);
  return (short)((u + r) >> 16);
}

// ---------------------------------------------------------------------------
// m97-style bf16 GEMM: C = op(A @ Bt^T).  A:(M,K) bf16 row-major, Bt:(N,K)
// bf16 row-major. 128x128 tile, BK=64, 256 thr = 4 waves of 64x64.
// global_load_lds width-16 staging, both-sides XOR swizzle (rule 21):
//   LDS[row*128 + kb] holds A[row][ (kb ^ ((row&7)<<4)) /2 ]
// BIAS: 0 none, 1 per-col, 2 per-row.
// ---------------------------------------------------------------------------
template<int BIAS, int RES, int RELU, int OF32, int OBF, int SWZ>
__global__ __launch_bounds__(256) void gemm_bt(
    const unsigned short* __restrict__ A, const unsigned short* __restrict__ Bt,
    const float* __restrict__ bias, const float* __restrict__ res,
    float* __restrict__ Cf, unsigned short* __restrict__ Cb,
    int lda, int ldb, int ldc, int ldcb, int ldr, int nk,
    long sA, long sB, long sC, long sCb, long sR) {
  __shared__ short Alds[128 * 64];
  __shared__ short Blds[128 * 64];
  int tid = threadIdx.x;
  int bx = blockIdx.x, by = blockIdx.y, bz = blockIdx.z;
  if (SWZ) {
    int nx = gridDim.x;
    int nwg = nx * gridDim.y;     // must be %8==0
    int id = by * nx + bx;
    int q = nwg >> 3;
    int nid = (id & 7) * q + (id >> 3);
    bx = nid % nx; by = nid / nx;
  }
  int bm0 = by * 128, bn0 = bx * 128;
  const char* Ag = (const char*)(A + bz * sA);
  const char* Bg = (const char*)(Bt + bz * sB);
  int w = tid >> 6, lane = tid & 63;
  int sr = tid >> 3;                       // 0..31 staging row within 32-row panel
  int skb = ((tid & 7) ^ (sr & 7)) << 4;   // inverse-swizzled source k-byte
  size_t la2 = (size_t)lda * 2, lb2 = (size_t)ldb * 2;
  char* Al = (char*)Alds + w * 1024;
  char* Bl = (char*)Blds + w * 1024;
  int wm = (w >> 1) * 64, wn = (w & 1) * 64;
  int rb = lane & 15;
  int kx = (lane & 7) << 4;                // read-side swizzle (row&7 == lane&7)
  int kb0 = (lane >> 4) << 4;
  const char* Ar = (const char*)Alds + (wm + rb) * 128;
  const char* Br = (const char*)Blds + (wn + rb) * 128;
  f4 acc[4][4] = {};
  for (int kt = 0; kt < nk; ++kt) {
    size_t ka = (size_t)kt * 128 + skb;
    __syncthreads();
#pragma unroll
    for (int p = 0; p < 4; ++p)
      __builtin_amdgcn_global_load_lds(
          (const __attribute__((address_space(1))) void*)(Ag + (size_t)(bm0 + p * 32 + sr) * la2 + ka),
          (__attribute__((address_space(3))) void*)(Al + p * 4096), 16, 0, 0);
#pragma unroll
    for (int p = 0; p < 4; ++p)
      __builtin_amdgcn_global_load_lds(
          (const __attribute__((address_space(1))) void*)(Bg + (size_t)(bn0 + p * 32 + sr) * lb2 + ka),
          (__attribute__((address_space(3))) void*)(Bl + p * 4096), 16, 0, 0);
    __syncthreads();
#pragma unroll
    for (int ks = 0; ks < 2; ++ks) {
      int kb = (kb0 + ks * 64) ^ kx;
      s8v a[4], b[4];
#pragma unroll
      for (int i = 0; i < 4; ++i) a[i] = *(const s8v*)(Ar + i * 2048 + kb);
#pragma unroll
      for (int j = 0; j < 4; ++j) b[j] = *(const s8v*)(Br + j * 2048 + kb);
#pragma unroll
      for (int i = 0; i < 4; ++i)
#pragma unroll
        for (int j = 0; j < 4; ++j)
          acc[i][j] = __builtin_amdgcn_mfma_f32_16x16x32_bf16(a[i], b[j], acc[i][j], 0, 0, 0);
    }
  }
  float* Cfp = Cf + bz * sC;
  unsigned short* Cbp = Cb + bz * sCb;
  const float* Rp = res + bz * sR;
#pragma unroll
  for (int i = 0; i < 4; ++i) {
    int row = bm0 + wm + i * 16 + (lane >> 4) * 4;
#pragma unroll
    for (int r = 0; r < 4; ++r) {
      int rr = row + r;
#pragma unroll
      for (int j = 0; j < 4; ++j) {
        int col = bn0 + wn + j * 16 + (lane & 15);
        float v = acc[i][j][r];
        if (BIAS == 1) v += bias[col];
        if (BIAS == 2) v += bias[rr];
        if (RELU) v = fmaxf(v, 0.f);
        if (RES) v += Rp[(size_t)rr * ldr + col];
        if (OF32) Cfp[(size_t)rr * ldc + col] = v;
        if (OBF) Cbp[(size_t)rr * ldcb + col] = (unsigned short)f2bf(v);
      }
    }
  }
}

// f32 (rows, cols) -> bf16 (cols, rows)
__global__ __launch_bounds__(256) void wtrans_k(const float* __restrict__ src,
                                                unsigned short* __restrict__ dst,
                                                int rows, int cols) {
  __shared__ float t[64][65];
  int c0 = blockIdx.x * 64, r0 = blockIdx.y * 64;
  int tx = threadIdx.x & 63, ty = threadIdx.x >> 6;
#pragma unroll
  for (int j = 0; j < 16; ++j) {
    int r = j * 4 + ty;
    t[r][tx] = src[(size_t)(r0 + r) * cols + c0 + tx];
  }
  __syncthreads();
#pragma unroll
  for (int j = 0; j < 16; ++j) {
    int n = j * 4 + ty;
    dst[(size_t)(c0 + n) * rows + r0 + tx] = (unsigned short)f2bf(t[tx][n]);
  }
}

__global__ __launch_bounds__(256) void convbf_k(const float* __restrict__ src,
                                                unsigned short* __restrict__ dst, int n4) {
  int i = blockIdx.x * 256 + threadIdx.x;
  if (i >= n4) return;
  f4 f = ((const f4*)src)[i];
  s4v v;
  v[0] = f2bf(f[0]); v[1] = f2bf(f[1]); v[2] = f2bf(f[2]); v[3] = f2bf(f[3]);
  ((s4v*)dst)[i] = v;
}

__device__ __forceinline__ float wave_max(float v) {
#pragma unroll
  for (int off = 32; off > 0; off >>= 1) v = fmaxf(v, __shfl_xor(v, off));
  return v;
}
__device__ __forceinline__ float wave_sum(float v) {
#pragma unroll
  for (int off = 32; off > 0; off >>= 1) v += __shfl_xor(v, off);
  return v;
}

template<int CAUSAL>
__global__ __launch_bounds__(256) void softmax_k(float* __restrict__ Sm,
                                                 unsigned short* __restrict__ Wb) {
  int row = blockIdx.x;  // b*512 + q
  int q = row & 511;
  int t = threadIdx.x;
  float* Sp = Sm + (size_t)row * 512;
  const float scale = 0.03125f;
  float v0 = Sp[t] * scale;
  float v1 = Sp[t + 256] * scale;
  if (CAUSAL) {
    if (t > q) v0 = -1.0e7f;
    if (t + 256 > q) v1 = -1.0e7f;
  }
  __shared__ float red[4], red2[4];
  int lane = t & 63, wid = t >> 6;
  float m = wave_max(fmaxf(v0, v1));
  if (lane == 0) red[wid] = m;
  __syncthreads();
  m = fmaxf(fmaxf(red[0], red[1]), fmaxf(red[2], red[3]));
  float e0 = __expf(v0 - m);
  float e1 = __expf(v1 - m);
  float s = wave_sum(e0 + e1);
  if (lane == 0) red2[wid] = s;
  __syncthreads();
  s = (red2[0] + red2[1]) + (red2[2] + red2[3]);
  float inv = 1.0f / s;
  float w0 = e0 * inv, w1 = e1 * inv;
  Sp[t] = w0;
  Sp[t + 256] = w1;
  unsigned short* wp = Wb + (size_t)row * 512;
  wp[t] = (unsigned short)f2bf(w0);
  wp[t + 256] = (unsigned short)f2bf(w1);
}

// out[b,k,q] = S[b,q,k]
__global__ __launch_bounds__(256) void transpose_k(const float* __restrict__ Sm,
                                                   float* __restrict__ out) {
  __shared__ float tile[64][65];
  int b = blockIdx.z;
  int q0 = blockIdx.x * 64, k0 = blockIdx.y * 64;
  const float* Sp = Sm + (size_t)b * 512 * 512;
  float* op = out + (size_t)b * 512 * 512;
  int tx = threadIdx.x & 63, ty = threadIdx.x >> 6;
#pragma unroll
  for (int j = 0; j < 16; ++j) {
    int qq = j * 4 + ty;
    tile[qq][tx] = Sp[(size_t)(q0 + qq) * 512 + k0 + tx];
  }
  __syncthreads();
#pragma unroll
  for (int j = 0; j < 16; ++j) {
    int kk = j * 4 + ty;
    op[(size_t)(k0 + kk) * 512 + q0 + tx] = tile[tx][kk];
  }
}

__global__ __launch_bounds__(256) void embed_pe_k(const int* __restrict__ ids,
                                                  const float* __restrict__ emb,
                                                  float* __restrict__ ctx,
                                                  unsigned short* __restrict__ ctxb) {
  int row = blockIdx.x;  // b*512 + s
  int s = row & 511;
  int t = threadIdx.x;
  int id = ids[row];
  f4 e = *(const f4*)(emb + (size_t)id * 1024 + t * 4);
  int j0 = 2 * t, j1 = 2 * t + 1;
  float fr0 = powf(10000.0f, -2.0f * (float)j0 / 1024.0f);
  float fr1 = powf(10000.0f, -2.0f * (float)j1 / 1024.0f);
  float s0, c0, s1, c1;
  sincosf((float)s * fr0, &s0, &c0);
  sincosf((float)s * fr1, &s1, &c1);
  f4 o;
  o[0] = e[0] + s0; o[1] = e[1] + c0; o[2] = e[2] + s1; o[3] = e[3] + c1;
  *(f4*)(ctx + (size_t)row * 1024 + t * 4) = o;
  s4v ob;
  ob[0] = f2bf(o[0]); ob[1] = f2bf(o[1]); ob[2] = f2bf(o[2]); ob[3] = f2bf(o[3]);
  *(s4v*)(ctxb + (size_t)row * 1024 + t * 4) = ob;
}

extern "C" void kernel_launch(void* const* d_in, const int* in_sizes, int n_in,
                              void* d_out, int out_size, void* d_ws, size_t ws_size,
                              hipStream_t stream) {
  const int B = 8, S = 512, H = 1024, V = 32000, L = 6;
  const int M = B * S;  // 4096

  const int* ids = (const int*)d_in[0];
  const float* ann = (const float*)d_in[1];
  const float* emb = (const float*)d_in[3];
  const float* Wf[7] = {(const float*)d_in[4],  (const float*)d_in[6],
                        (const float*)d_in[8],  (const float*)d_in[10],
                        (const float*)d_in[12], (const float*)d_in[14],
                        (const float*)d_in[16]};
  const float* bq_s = (const float*)d_in[5];
  const float* bk_s = (const float*)d_in[7];
  const float* bv_s = (const float*)d_in[9];
  const float* bq_c = (const float*)d_in[11];
  const float* bk_c = (const float*)d_in[13];
  const float* bv_c = (const float*)d_in[15];
  const float* bm = (const float*)d_in[17];
  const float* Wout = (const float*)d_in[18];
  const float* bout = (const float*)d_in[19];
  float* out = (float*)d_out;

  char* ws = (char*)d_ws;
  if (ws_size < ((size_t)164 << 20)) return;
  float* X0 = (float*)ws;                                       // 16MB ctx f32 ping
  float* X1 = (float*)(ws + ((size_t)16 << 20));                // 16MB pong
  unsigned short* XbfA = (unsigned short*)(ws + ((size_t)32 << 20));  // 8MB ctx bf16
  unsigned short* XbfB = (unsigned short*)(ws + ((size_t)40 << 20));  // 8MB R1 bf16
  unsigned short* XbfC = (unsigned short*)(ws + ((size_t)48 << 20));  // 8MB R2 bf16
  unsigned short* Qbf = (unsigned short*)(ws + ((size_t)56 << 20));   // 8MB
  unsigned short* Kbf = (unsigned short*)(ws + ((size_t)64 << 20));   // 8MB
  unsigned short* Vtbf = (unsigned short*)(ws + ((size_t)72 << 20));  // 8MB (H,4096)
  float* Sf = (float*)(ws + ((size_t)80 << 20));                // 8MB scores f32
  unsigned short* Wbf = (unsigned short*)(ws + ((size_t)88 << 20));   // 4MB weights bf16
  unsigned short* annbf = (unsigned short*)(ws + ((size_t)92 << 20)); // 8MB
  unsigned short* WT = (unsigned short*)(ws + ((size_t)100 << 20));   // 64MB transposed wts

  size_t enc_off = (size_t)M * V;
  size_t self_off = enc_off + (size_t)L * B * S * S;

  long sQ = (long)S * H;
  long sS = (long)S * S;

  embed_pe_k<<<M, 256, 0, stream>>>(ids, emb, X0, XbfA);
  convbf_k<<<(M * H / 4 + 255) / 256, 256, 0, stream>>>(ann, annbf, M * H / 4);

  float* P = X0;
  float* Palt = X1;
  const size_t WSZ = (size_t)H * H;  // 1M elements

  for (int l = 0; l < L; ++l) {
    size_t wo = (size_t)l * WSZ;
    size_t bo = (size_t)l * H;
    unsigned short* WqT = WT;            // self q,k,v ; cross q,k,v ; m
    unsigned short* WkT = WT + WSZ;
    unsigned short* WvT = WT + 2 * WSZ;
    unsigned short* WqcT = WT + 3 * WSZ;
    unsigned short* WkcT = WT + 4 * WSZ;
    unsigned short* WvcT = WT + 5 * WSZ;
    unsigned short* WmT = WT + 6 * WSZ;
    for (int wi = 0; wi < 7; ++wi)
      wtrans_k<<<dim3(16, 16), 256, 0, stream>>>(Wf[wi] + wo, WT + wi * WSZ, H, H);

    // ---- self attention ----
    gemm_bt<1, 0, 0, 0, 1, 0><<<dim3(8, 32), 256, 0, stream>>>(
        XbfA, WqT, bq_s + bo, nullptr, nullptr, Qbf,
        H, H, 0, H, 0, 16, 0, 0, 0, 0, 0);
    gemm_bt<1, 0, 0, 0, 1, 0><<<dim3(8, 32), 256, 0, stream>>>(
        XbfA, WkT, bk_s + bo, nullptr, nullptr, Kbf,
        H, H, 0, H, 0, 16, 0, 0, 0, 0, 0);
    // Vt = (X @ Wv)^T : A=WvT (H,H), B=XbfA (M,H) -> C (H, M), bias per-row
    gemm_bt<2, 0, 0, 0, 1, 0><<<dim3(32, 8), 256, 0, stream>>>(
        WvT, XbfA, bv_s + bo, nullptr, nullptr, Vtbf,
        H, H, 0, M, 0, 16, 0, 0, 0, 0, 0);
    // scores[b] = Q[b] @ K[b]^T
    gemm_bt<0, 0, 0, 1, 0, 0><<<dim3(4, 4, B), 256, 0, stream>>>(
        Qbf, Kbf, nullptr, nullptr, Sf, nullptr,
        H, H, S, 0, 0, 16, sQ, sQ, sS, 0, 0);
    softmax_k<1><<<M, 256, 0, stream>>>(Sf, Wbf);
    transpose_k<<<dim3(8, 8, B), 256, 0, stream>>>(Sf, out + self_off + (size_t)l * B * S * S);
    // R1 = P + W @ V : A=Wbf (S,S) per batch, B=Vt + b*512 (H rows, ldb=M)
    gemm_bt<0, 1, 0, 1, 1, 0><<<dim3(8, 4, B), 256, 0, stream>>>(
        Wbf, Vtbf, nullptr, P, Palt, XbfB,
        S, M, H, H, H, 8, sS, S, sQ, sQ, sQ);
    // ---- cross attention ----
    gemm_bt<1, 0, 0, 0, 1, 0><<<dim3(8, 32), 256, 0, stream>>>(
        XbfB, WqcT, bq_c + bo, nullptr, nullptr, Qbf,
        H, H, 0, H, 0, 16, 0, 0, 0, 0, 0);
    gemm_bt<1, 0, 0, 0, 1, 0><<<dim3(8, 32), 256, 0, stream>>>(
        annbf, WkcT, bk_c + bo, nullptr, nullptr, Kbf,
        H, H, 0, H, 0, 16, 0, 0, 0, 0, 0);
    gemm_bt<2, 0, 0, 0, 1, 0><<<dim3(32, 8), 256, 0, stream>>>(
        WvcT, annbf, bv_c + bo, nullptr, nullptr, Vtbf,
        H, H, 0, M, 0, 16, 0, 0, 0, 0, 0);
    gemm_bt<0, 0, 0, 1, 0, 0><<<dim3(4, 4, B), 256, 0, stream>>>(
        Qbf, Kbf, nullptr, nullptr, Sf, nullptr,
        H, H, S, 0, 0, 16, sQ, sQ, sS, 0, 0);
    softmax_k<0><<<M, 256, 0, stream>>>(Sf, Wbf);
    transpose_k<<<dim3(8, 8, B), 256, 0, stream>>>(Sf, out + enc_off + (size_t)l * B * S * S);
    // R2 = R1 + W @ V
    gemm_bt<0, 1, 0, 1, 1, 0><<<dim3(8, 4, B), 256, 0, stream>>>(
        Wbf, Vtbf, nullptr, Palt, P, XbfC,
        S, M, H, H, H, 8, sS, S, sQ, sQ, sQ);
    // ctx' = R2 + relu(R2 @ Wm + bm)
    gemm_bt<1, 1, 1, 1, 1, 0><<<dim3(8, 32), 256, 0, stream>>>(
        XbfC, WmT, bm + bo, P, Palt, XbfA,
        H, H, H, H, H, 16, 0, 0, 0, 0, 0);
    float* t = P; P = Palt; Palt = t;
  }

  // WoutT (V, H) bf16
  wtrans_k<<<dim3(V / 64, H / 64), 256, 0, stream>>>(Wout, WT, H, V);
  // logits = ctx @ Wout + bout   (XCD-swizzled: 8000 blocks)
  gemm_bt<1, 0, 0, 1, 0, 1><<<dim3(V / 128, M / 128), 256, 0, stream>>>(
      XbfA, WT, bout, nullptr, out, nullptr,
      H, H, V, 0, 0, 16, 0, 0, 0, 0, 0);
}

// Round 3
// 1999.132 us; speedup vs baseline: 1.9108x; 1.0947x over previous
//
#include <hip/hip_runtime.h>

typedef __attribute__((ext_vector_type(4))) float f4;
typedef __attribute__((ext_vector_type(8))) short s8v;
typedef __attribute__((ext_vector_type(4))) short s4v;

__device__ __forceinline__ short f2bf(float f) {
  union { float f; unsigned int u; } v; v.f = f;
  unsigned int u = v.u;
  unsigned int r = 0x7fffu + ((u >> 16) & 1u);
  return (short)((u + r) >> 16);
}

// ---------------------------------------------------------------------------
// m97-style bf16 GEMM: C = op(A @ Bt^T).  A:(M,K) bf16 row-major, Bt:(N,K)
// bf16 row-major. 128x128 tile, BK=64, 256 thr = 4 waves of 64x64.
// global_load_lds width-16 staging, both-sides XOR swizzle.
// BIAS: 0 none, 1 per-col, 2 per-row, 3 split per-col (bias | bias2 at 1024).
// ---------------------------------------------------------------------------
template<int BIAS, int RES, int RELU, int OF32, int OBF, int SWZ>
__global__ __launch_bounds__(256) void gemm_bt(
    const unsigned short* __restrict__ A, const unsigned short* __restrict__ Bt,
    const float* __restrict__ bias, const float* __restrict__ bias2,
    const float* __restrict__ res,
    float* __restrict__ Cf, unsigned short* __restrict__ Cb,
    int lda, int ldb, int ldc, int ldcb, int ldr, int nk,
    long sA, long sB, long sC, long sCb, long sR) {
  __shared__ short Alds[128 * 64];
  __shared__ short Blds[128 * 64];
  int tid = threadIdx.x;
  int bx = blockIdx.x, by = blockIdx.y, bz = blockIdx.z;
  if (SWZ) {
    int nx = gridDim.x;
    int nwg = nx * gridDim.y;     // must be %8==0
    int id = by * nx + bx;
    int q = nwg >> 3;
    int nid = (id & 7) * q + (id >> 3);
    bx = nid % nx; by = nid / nx;
  }
  int bm0 = by * 128, bn0 = bx * 128;
  const char* Ag = (const char*)(A + bz * sA);
  const char* Bg = (const char*)(Bt + bz * sB);
  int w = tid >> 6, lane = tid & 63;
  int sr = tid >> 3;                       // 0..31 staging row within 32-row panel
  int skb = ((tid & 7) ^ (sr & 7)) << 4;   // inverse-swizzled source k-byte
  size_t la2 = (size_t)lda * 2, lb2 = (size_t)ldb * 2;
  char* Al = (char*)Alds + w * 1024;
  char* Bl = (char*)Blds + w * 1024;
  int wm = (w >> 1) * 64, wn = (w & 1) * 64;
  int rb = lane & 15;
  int kx = (lane & 7) << 4;                // read-side swizzle
  int kb0 = (lane >> 4) << 4;
  const char* Ar = (const char*)Alds + (wm + rb) * 128;
  const char* Br = (const char*)Blds + (wn + rb) * 128;
  f4 acc[4][4] = {};
  for (int kt = 0; kt < nk; ++kt) {
    size_t ka = (size_t)kt * 128 + skb;
    __syncthreads();
#pragma unroll
    for (int p = 0; p < 4; ++p)
      __builtin_amdgcn_global_load_lds(
          (const __attribute__((address_space(1))) void*)(Ag + (size_t)(bm0 + p * 32 + sr) * la2 + ka),
          (__attribute__((address_space(3))) void*)(Al + p * 4096), 16, 0, 0);
#pragma unroll
    for (int p = 0; p < 4; ++p)
      __builtin_amdgcn_global_load_lds(
          (const __attribute__((address_space(1))) void*)(Bg + (size_t)(bn0 + p * 32 + sr) * lb2 + ka),
          (__attribute__((address_space(3))) void*)(Bl + p * 4096), 16, 0, 0);
    __syncthreads();
#pragma unroll
    for (int ks = 0; ks < 2; ++ks) {
      int kb = (kb0 + ks * 64) ^ kx;
      s8v a[4], b[4];
#pragma unroll
      for (int i = 0; i < 4; ++i) a[i] = *(const s8v*)(Ar + i * 2048 + kb);
#pragma unroll
      for (int j = 0; j < 4; ++j) b[j] = *(const s8v*)(Br + j * 2048 + kb);
#pragma unroll
      for (int i = 0; i < 4; ++i)
#pragma unroll
        for (int j = 0; j < 4; ++j)
          acc[i][j] = __builtin_amdgcn_mfma_f32_16x16x32_bf16(a[i], b[j], acc[i][j], 0, 0, 0);
    }
  }
  float* Cfp = Cf + bz * sC;
  unsigned short* Cbp = Cb + bz * sCb;
  const float* Rp = res + bz * sR;
#pragma unroll
  for (int i = 0; i < 4; ++i) {
    int row = bm0 + wm + i * 16 + (lane >> 4) * 4;
#pragma unroll
    for (int r = 0; r < 4; ++r) {
      int rr = row + r;
#pragma unroll
      for (int j = 0; j < 4; ++j) {
        int col = bn0 + wn + j * 16 + (lane & 15);
        float v = acc[i][j][r];
        if (BIAS == 1) v += bias[col];
        if (BIAS == 2) v += bias[rr];
        if (BIAS == 3) v += (col < 1024) ? bias[col] : bias2[col - 1024];
        if (RELU) v = fmaxf(v, 0.f);
        if (RES) v += Rp[(size_t)rr * ldr + col];
        if (OF32) Cfp[(size_t)rr * ldc + col] = v;
        if (OBF) Cbp[(size_t)rr * ldcb + col] = (unsigned short)f2bf(v);
      }
    }
  }
}

// 64x64 tile transpose: f32 (rows, cols) -> bf16 (cols, rows)
__device__ __forceinline__ void wtrans_tile(const float* src, unsigned short* dst,
                                            int rows, int cols, int c0, int r0) {
  __shared__ float t[64][65];
  int tx = threadIdx.x & 63, ty = threadIdx.x >> 6;
#pragma unroll
  for (int j = 0; j < 16; ++j) {
    int r = j * 4 + ty;
    t[r][tx] = src[(size_t)(r0 + r) * cols + c0 + tx];
  }
  __syncthreads();
#pragma unroll
  for (int j = 0; j < 16; ++j) {
    int n = j * 4 + ty;
    dst[(size_t)(c0 + n) * rows + r0 + tx] = (unsigned short)f2bf(t[tx][n]);
  }
}

__global__ __launch_bounds__(256) void wtrans_k(const float* __restrict__ src,
                                                unsigned short* __restrict__ dst,
                                                int rows, int cols) {
  wtrans_tile(src, dst, rows, cols, blockIdx.x * 64, blockIdx.y * 64);
}

// All 42 H x H weight transposes in one launch. z = l*7 + wi.
__global__ __launch_bounds__(256) void wtrans_all_k(
    const float* __restrict__ w0, const float* __restrict__ w1,
    const float* __restrict__ w2, const float* __restrict__ w3,
    const float* __restrict__ w4, const float* __restrict__ w5,
    const float* __restrict__ w6, unsigned short* __restrict__ dst) {
  int z = blockIdx.z;
  int l = z / 7, wi = z % 7;
  const float* src;
  switch (wi) {
    case 0: src = w0; break;
    case 1: src = w1; break;
    case 2: src = w2; break;
    case 3: src = w3; break;
    case 4: src = w4; break;
    case 5: src = w5; break;
    default: src = w6; break;
  }
  src += (size_t)l * 1024 * 1024;
  unsigned short* d = dst + (size_t)z * 1024 * 1024;
  wtrans_tile(src, d, 1024, 1024, blockIdx.x * 64, blockIdx.y * 64);
}

__global__ __launch_bounds__(256) void convbf_k(const float* __restrict__ src,
                                                unsigned short* __restrict__ dst, int n4) {
  int i = blockIdx.x * 256 + threadIdx.x;
  if (i >= n4) return;
  f4 f = ((const f4*)src)[i];
  s4v v;
  v[0] = f2bf(f[0]); v[1] = f2bf(f[1]); v[2] = f2bf(f[2]); v[3] = f2bf(f[3]);
  ((s4v*)dst)[i] = v;
}

// ---------------------------------------------------------------------------
// Fused softmax + transpose. Sf: (B, Sq, Sk) raw scores f32.
// outT: (B, Sk, Sq) f32 normalized (to d_out). Wb: (B, Sq, Sk) bf16 normalized.
// Block: 16 q-rows x 512 k. Grid (32, B).
// ---------------------------------------------------------------------------
template<int CAUSAL>
__global__ __launch_bounds__(256) void smt_k(const float* __restrict__ Sf,
                                             float* __restrict__ outT,
                                             unsigned short* __restrict__ Wb) {
  __shared__ float T[16][520];
  int b = blockIdx.y;
  int q0 = blockIdx.x * 16;
  int t = threadIdx.x;
  const float* Sp = Sf + ((size_t)b * 512 + q0) * 512;
#pragma unroll
  for (int j = 0; j < 8; ++j) {
    int idx = t + 256 * j;            // f4 index over 16x128
    int r = idx >> 7, c4 = idx & 127;
    f4 v = *(const f4*)(Sp + (size_t)r * 512 + c4 * 4);
    *(f4*)&T[r][c4 * 4] = v;
  }
  __syncthreads();
  int w = t >> 6, l = t & 63;
  int r = 4 * w + (l >> 4);
  int l16 = l & 15;
  int q = q0 + r;
  const float scale = 0.03125f;
  float v[32];
#pragma unroll
  for (int j = 0; j < 32; ++j) {
    int k = l16 + 16 * j;
    float x = T[r][k] * scale;
    if (CAUSAL && k > q) x += -1.0e7f;
    v[j] = x;
  }
  float m = v[0];
#pragma unroll
  for (int j = 1; j < 32; ++j) m = fmaxf(m, v[j]);
  m = fmaxf(m, __shfl_xor(m, 1)); m = fmaxf(m, __shfl_xor(m, 2));
  m = fmaxf(m, __shfl_xor(m, 4)); m = fmaxf(m, __shfl_xor(m, 8));
  float s = 0.f;
#pragma unroll
  for (int j = 0; j < 32; ++j) { v[j] = __expf(v[j] - m); s += v[j]; }
  s += __shfl_xor(s, 1); s += __shfl_xor(s, 2);
  s += __shfl_xor(s, 4); s += __shfl_xor(s, 8);
  float inv = 1.0f / s;
#pragma unroll
  for (int j = 0; j < 32; ++j) T[r][l16 + 16 * j] = v[j] * inv;
  __syncthreads();
  // transposed f32 write: out[k][q0 + ql]
  float* op = outT + (size_t)b * 512 * 512 + q0;
  int ql = t & 15, kb = t >> 4;
#pragma unroll
  for (int i = 0; i < 32; ++i) {
    int k = kb + 16 * i;
    op[(size_t)k * 512 + ql] = T[ql][k];
  }
  // bf16 (q,k) write
  unsigned short* wp = Wb + ((size_t)b * 512 + q0) * 512;
#pragma unroll
  for (int i = 0; i < 4; ++i) {
    int rr = 4 * w + i;
    const float* row = &T[rr][l * 8];
    s8v o;
#pragma unroll
    for (int j = 0; j < 8; ++j) o[j] = f2bf(row[j]);
    *(s8v*)(wp + (size_t)rr * 512 + l * 8) = o;
  }
}

__global__ __launch_bounds__(256) void embed_pe_k(const int* __restrict__ ids,
                                                  const float* __restrict__ emb,
                                                  float* __restrict__ ctx,
                                                  unsigned short* __restrict__ ctxb) {
  int row = blockIdx.x;  // b*512 + s
  int s = row & 511;
  int t = threadIdx.x;
  int id = ids[row];
  f4 e = *(const f4*)(emb + (size_t)id * 1024 + t * 4);
  int j0 = 2 * t, j1 = 2 * t + 1;
  float fr0 = powf(10000.0f, -2.0f * (float)j0 / 1024.0f);
  float fr1 = powf(10000.0f, -2.0f * (float)j1 / 1024.0f);
  float s0, c0, s1, c1;
  sincosf((float)s * fr0, &s0, &c0);
  sincosf((float)s * fr1, &s1, &c1);
  f4 o;
  o[0] = e[0] + s0; o[1] = e[1] + c0; o[2] = e[2] + s1; o[3] = e[3] + c1;
  *(f4*)(ctx + (size_t)row * 1024 + t * 4) = o;
  s4v ob;
  ob[0] = f2bf(o[0]); ob[1] = f2bf(o[1]); ob[2] = f2bf(o[2]); ob[3] = f2bf(o[3]);
  *(s4v*)(ctxb + (size_t)row * 1024 + t * 4) = ob;
}

extern "C" void kernel_launch(void* const* d_in, const int* in_sizes, int n_in,
                              void* d_out, int out_size, void* d_ws, size_t ws_size,
                              hipStream_t stream) {
  const int B = 8, S = 512, H = 1024, V = 32000, L = 6;
  const int M = B * S;  // 4096

  const int* ids = (const int*)d_in[0];
  const float* ann = (const float*)d_in[1];
  const float* emb = (const float*)d_in[3];
  const float* bq_s = (const float*)d_in[5];
  const float* bk_s = (const float*)d_in[7];
  const float* bv_s = (const float*)d_in[9];
  const float* bq_c = (const float*)d_in[11];
  const float* bk_c = (const float*)d_in[13];
  const float* bv_c = (const float*)d_in[15];
  const float* bm = (const float*)d_in[17];
  const float* Wout = (const float*)d_in[18];
  const float* bout = (const float*)d_in[19];
  float* out = (float*)d_out;

  char* ws = (char*)d_ws;
  if (ws_size < ((size_t)164 << 20)) return;
  float* X0 = (float*)ws;                                             // 16MB residual ping
  float* X1 = (float*)(ws + ((size_t)16 << 20));                      // 16MB residual pong
  unsigned short* Xs0 = (unsigned short*)(ws + ((size_t)32 << 20));   // 8MB bf16 slot 0
  unsigned short* Xs1 = (unsigned short*)(ws + ((size_t)40 << 20));   // 8MB bf16 slot 1
  unsigned short* QKbf = (unsigned short*)(ws + ((size_t)48 << 20));  // 16MB (4096,2048)
  unsigned short* Wbf = QKbf;                                         // alias (dead when used)
  unsigned short* Vtbf = (unsigned short*)(ws + ((size_t)64 << 20));  // 8MB (H,4096)
  unsigned short* annbf = (unsigned short*)(ws + ((size_t)72 << 20)); // 8MB
  unsigned short* WT = (unsigned short*)(ws + ((size_t)80 << 20));    // 84MB: 42 x (H,H)

  size_t enc_off = (size_t)M * V;
  size_t self_off = enc_off + (size_t)L * B * S * S;

  long sQ = (long)S * H;
  long sS = (long)S * S;
  const size_t WSZ = (size_t)H * H;

  embed_pe_k<<<M, 256, 0, stream>>>(ids, emb, X0, Xs0);
  convbf_k<<<(M * H / 4 + 255) / 256, 256, 0, stream>>>(ann, annbf, M * H / 4);
  wtrans_all_k<<<dim3(16, 16, 42), 256, 0, stream>>>(
      (const float*)d_in[4], (const float*)d_in[6], (const float*)d_in[8],
      (const float*)d_in[10], (const float*)d_in[12], (const float*)d_in[14],
      (const float*)d_in[16], WT);

  float* P = X0;
  float* Palt = X1;
  unsigned short* Xa = Xs0;
  unsigned short* Xb = Xs1;

  for (int l = 0; l < L; ++l) {
    size_t bo = (size_t)l * H;
    unsigned short* WTl = WT + (size_t)l * 7 * WSZ;
    unsigned short* WqkT = WTl;              // Wq^T then Wk^T (contiguous)
    unsigned short* WvT = WTl + 2 * WSZ;
    unsigned short* WqcT = WTl + 3 * WSZ;
    unsigned short* WkcT = WTl + 4 * WSZ;
    unsigned short* WvcT = WTl + 5 * WSZ;
    unsigned short* WmT = WTl + 6 * WSZ;

    // ---- self attention ----
    // Q|K = X @ [Wq Wk] : (4096, 2048)
    gemm_bt<3, 0, 0, 0, 1, 0><<<dim3(16, 32), 256, 0, stream>>>(
        Xa, WqkT, bq_s + bo, bk_s + bo, nullptr, nullptr, QKbf,
        H, H, 0, 2048, 0, 16, 0, 0, 0, 0, 0);
    // Vt = (X @ Wv)^T : (H, 4096)
    gemm_bt<2, 0, 0, 0, 1, 0><<<dim3(32, 8), 256, 0, stream>>>(
        WvT, Xa, bv_s + bo, nullptr, nullptr, nullptr, Vtbf,
        H, H, 0, M, 0, 16, 0, 0, 0, 0, 0);
    // raw scores (b,q,k) -> Palt (dead f32 buffer)
    gemm_bt<0, 0, 0, 1, 0, 0><<<dim3(4, 4, B), 256, 0, stream>>>(
        QKbf, QKbf + 1024, nullptr, nullptr, nullptr, Palt, nullptr,
        2048, 2048, S, 0, 0, 16, (long)S * 2048, (long)S * 2048, sS, 0, 0);
    smt_k<1><<<dim3(32, B), 256, 0, stream>>>(
        Palt, out + self_off + (size_t)l * B * S * S, Wbf);
    // R1 = P + W @ V : f32 -> Palt, bf16 -> Xb
    gemm_bt<0, 1, 0, 1, 1, 0><<<dim3(8, 4, B), 256, 0, stream>>>(
        Wbf, Vtbf, nullptr, nullptr, P, Palt, Xb,
        S, M, H, H, H, 8, sS, S, sQ, sQ, sQ);
    // ---- cross attention ----
    gemm_bt<1, 0, 0, 0, 1, 0><<<dim3(8, 32), 256, 0, stream>>>(
        Xb, WqcT, bq_c + bo, nullptr, nullptr, nullptr, QKbf,
        H, H, 0, 2048, 0, 16, 0, 0, 0, 0, 0);
    gemm_bt<1, 0, 0, 0, 1, 0><<<dim3(8, 32), 256, 0, stream>>>(
        annbf, WkcT, bk_c + bo, nullptr, nullptr, nullptr, QKbf + 1024,
        H, H, 0, 2048, 0, 16, 0, 0, 0, 0, 0);
    gemm_bt<2, 0, 0, 0, 1, 0><<<dim3(32, 8), 256, 0, stream>>>(
        WvcT, annbf, bv_c + bo, nullptr, nullptr, nullptr, Vtbf,
        H, H, 0, M, 0, 16, 0, 0, 0, 0, 0);
    // raw scores -> P (dead f32 buffer)
    gemm_bt<0, 0, 0, 1, 0, 0><<<dim3(4, 4, B), 256, 0, stream>>>(
        QKbf, QKbf + 1024, nullptr, nullptr, nullptr, P, nullptr,
        2048, 2048, S, 0, 0, 16, (long)S * 2048, (long)S * 2048, sS, 0, 0);
    smt_k<0><<<dim3(32, B), 256, 0, stream>>>(
        P, out + enc_off + (size_t)l * B * S * S, Wbf);
    // R2 = R1 + W @ V : f32 -> P, bf16 -> Xa
    gemm_bt<0, 1, 0, 1, 1, 0><<<dim3(8, 4, B), 256, 0, stream>>>(
        Wbf, Vtbf, nullptr, nullptr, Palt, P, Xa,
        S, M, H, H, H, 8, sS, S, sQ, sQ, sQ);
    // ctx' = R2 + relu(R2 @ Wm + bm) : f32 -> Palt, bf16 -> Xb
    gemm_bt<1, 1, 1, 1, 1, 0><<<dim3(8, 32), 256, 0, stream>>>(
        Xa, WmT, bm + bo, nullptr, P, Palt, Xb,
        H, H, H, H, H, 16, 0, 0, 0, 0, 0);
    float* tf = P; P = Palt; Palt = tf;
    unsigned short* tb = Xa; Xa = Xb; Xb = tb;
  }

  // WoutT (V, H) bf16 -> overlay WT region (weights no longer needed)
  wtrans_k<<<dim3(V / 64, H / 64), 256, 0, stream>>>(Wout, WT, H, V);
  // logits = ctx @ Wout + bout   (XCD-swizzled: 8000 blocks)
  gemm_bt<1, 0, 0, 1, 0, 1><<<dim3(V / 128, M / 128), 256, 0, stream>>>(
      Xa, WT, bout, nullptr, nullptr, out, nullptr,
      H, H, V, 0, 0, 16, 0, 0, 0, 0, 0);
}

// Round 4
// 1811.906 us; speedup vs baseline: 2.1083x; 1.1033x over previous
//
#include <hip/hip_runtime.h>

typedef __attribute__((ext_vector_type(4))) float f4;
typedef __attribute__((ext_vector_type(8))) short s8v;
typedef __attribute__((ext_vector_type(4))) short s4v;

__device__ __forceinline__ short f2bf(float f) {
  union { float f; unsigned int u; } v; v.f = f;
  unsigned int u = v.u;
  unsigned int r = 0x7fffu + ((u >> 16) & 1u);
  return (short)((u + r) >> 16);
}

// ---------------------------------------------------------------------------
// m97-style bf16 GEMM: C = op(A @ Bt^T).  A:(M,K) bf16 row-major, Bt:(N,K)
// bf16 row-major. 128x128 tile, BK=64, 256 thr = 4 waves of 64x64.
// global_load_lds width-16 staging, both-sides XOR swizzle.
// BIAS: 0 none, 1 per-col, 2 per-row, 3 split per-col (bias | bias2 at 1024).
// SWZ: 0 none, 1 row-chunk XCD swizzle, 2 col-chunk XCD swizzle.
// ---------------------------------------------------------------------------
template<int BIAS, int RES, int RELU, int OF32, int OBF, int SWZ>
__global__ __launch_bounds__(256) void gemm_bt(
    const unsigned short* __restrict__ A, const unsigned short* __restrict__ Bt,
    const float* __restrict__ bias, const float* __restrict__ bias2,
    const float* __restrict__ res,
    float* __restrict__ Cf, unsigned short* __restrict__ Cb,
    int lda, int ldb, int ldc, int ldcb, int ldr, int nk,
    long sA, long sB, long sC, long sCb, long sR, long sBias) {
  __shared__ short Alds[128 * 64];
  __shared__ short Blds[128 * 64];
  int tid = threadIdx.x;
  int bx = blockIdx.x, by = blockIdx.y, bz = blockIdx.z;
  if (SWZ == 1) {
    int nx = gridDim.x;
    int nwg = nx * gridDim.y;     // must be %8==0
    int id = by * nx + bx;
    int q = nwg >> 3;
    int nid = (id & 7) * q + (id >> 3);
    bx = nid % nx; by = nid / nx;
  }
  if (SWZ == 2) {
    int gy = gridDim.y;
    int nwg = gridDim.x * gy;     // must be %8==0
    int id = by * gridDim.x + bx;
    int q = nwg >> 3;
    int c = (id & 7) * q + (id >> 3);
    by = c % gy; bx = c / gy;     // col-chunk: each XCD owns contiguous cols
  }
  int bm0 = by * 128, bn0 = bx * 128;
  const char* Ag = (const char*)(A + bz * sA);
  const char* Bg = (const char*)(Bt + bz * sB);
  if (BIAS) { bias += bz * sBias; if (BIAS == 3) bias2 += bz * sBias; }
  int w = tid >> 6, lane = tid & 63;
  int sr = tid >> 3;                       // 0..31 staging row within 32-row panel
  int skb = ((tid & 7) ^ (sr & 7)) << 4;   // inverse-swizzled source k-byte
  size_t la2 = (size_t)lda * 2, lb2 = (size_t)ldb * 2;
  char* Al = (char*)Alds + w * 1024;
  char* Bl = (char*)Blds + w * 1024;
  int wm = (w >> 1) * 64, wn = (w & 1) * 64;
  int rb = lane & 15;
  int kx = (lane & 7) << 4;                // read-side swizzle
  int kb0 = (lane >> 4) << 4;
  const char* Ar = (const char*)Alds + (wm + rb) * 128;
  const char* Br = (const char*)Blds + (wn + rb) * 128;
  f4 acc[4][4] = {};
  for (int kt = 0; kt < nk; ++kt) {
    size_t ka = (size_t)kt * 128 + skb;
    __syncthreads();
#pragma unroll
    for (int p = 0; p < 4; ++p)
      __builtin_amdgcn_global_load_lds(
          (const __attribute__((address_space(1))) void*)(Ag + (size_t)(bm0 + p * 32 + sr) * la2 + ka),
          (__attribute__((address_space(3))) void*)(Al + p * 4096), 16, 0, 0);
#pragma unroll
    for (int p = 0; p < 4; ++p)
      __builtin_amdgcn_global_load_lds(
          (const __attribute__((address_space(1))) void*)(Bg + (size_t)(bn0 + p * 32 + sr) * lb2 + ka),
          (__attribute__((address_space(3))) void*)(Bl + p * 4096), 16, 0, 0);
    __syncthreads();
#pragma unroll
    for (int ks = 0; ks < 2; ++ks) {
      int kb = (kb0 + ks * 64) ^ kx;
      s8v a[4], b[4];
#pragma unroll
      for (int i = 0; i < 4; ++i) a[i] = *(const s8v*)(Ar + i * 2048 + kb);
#pragma unroll
      for (int j = 0; j < 4; ++j) b[j] = *(const s8v*)(Br + j * 2048 + kb);
#pragma unroll
      for (int i = 0; i < 4; ++i)
#pragma unroll
        for (int j = 0; j < 4; ++j)
          acc[i][j] = __builtin_amdgcn_mfma_f32_16x16x32_bf16(a[i], b[j], acc[i][j], 0, 0, 0);
    }
  }
  float* Cfp = Cf + bz * sC;
  unsigned short* Cbp = Cb + bz * sCb;
  const float* Rp = res + bz * sR;
#pragma unroll
  for (int i = 0; i < 4; ++i) {
    int row = bm0 + wm + i * 16 + (lane >> 4) * 4;
#pragma unroll
    for (int r = 0; r < 4; ++r) {
      int rr = row + r;
#pragma unroll
      for (int j = 0; j < 4; ++j) {
        int col = bn0 + wn + j * 16 + (lane & 15);
        float v = acc[i][j][r];
        if (BIAS == 1) v += bias[col];
        if (BIAS == 2) v += bias[rr];
        if (BIAS == 3) v += (col < 1024) ? bias[col] : bias2[col - 1024];
        if (RELU) v = fmaxf(v, 0.f);
        if (RES) v += Rp[(size_t)rr * ldr + col];
        if (OF32) Cfp[(size_t)rr * ldc + col] = v;
        if (OBF) Cbp[(size_t)rr * ldcb + col] = (unsigned short)f2bf(v);
      }
    }
  }
}

// ---------------------------------------------------------------------------
// 64x64-tile variant for small batched GEMMs (scores, PV): 4 waves of 32x32.
// Same staging/swizzle formulas, higher block count.
// ---------------------------------------------------------------------------
template<int RES, int OF32, int OBF>
__global__ __launch_bounds__(256) void gemm64(
    const unsigned short* __restrict__ A, const unsigned short* __restrict__ Bt,
    const float* __restrict__ res,
    float* __restrict__ Cf, unsigned short* __restrict__ Cb,
    int lda, int ldb, int ldc, int ldcb, int ldr, int nk,
    long sA, long sB, long sC, long sCb, long sR) {
  __shared__ short Alds[64 * 64];
  __shared__ short Blds[64 * 64];
  int tid = threadIdx.x;
  int bx = blockIdx.x, by = blockIdx.y, bz = blockIdx.z;
  int bm0 = by * 64, bn0 = bx * 64;
  const char* Ag = (const char*)(A + bz * sA);
  const char* Bg = (const char*)(Bt + bz * sB);
  int w = tid >> 6, lane = tid & 63;
  int sr = tid >> 3;
  int skb = ((tid & 7) ^ (sr & 7)) << 4;
  size_t la2 = (size_t)lda * 2, lb2 = (size_t)ldb * 2;
  char* Al = (char*)Alds + w * 1024;
  char* Bl = (char*)Blds + w * 1024;
  int wm = (w >> 1) * 32, wn = (w & 1) * 32;
  int rb = lane & 15;
  int kx = (lane & 7) << 4;
  int kb0 = (lane >> 4) << 4;
  const char* Ar = (const char*)Alds + (wm + rb) * 128;
  const char* Br = (const char*)Blds + (wn + rb) * 128;
  f4 acc[2][2] = {};
  for (int kt = 0; kt < nk; ++kt) {
    size_t ka = (size_t)kt * 128 + skb;
    __syncthreads();
#pragma unroll
    for (int p = 0; p < 2; ++p)
      __builtin_amdgcn_global_load_lds(
          (const __attribute__((address_space(1))) void*)(Ag + (size_t)(bm0 + p * 32 + sr) * la2 + ka),
          (__attribute__((address_space(3))) void*)(Al + p * 4096), 16, 0, 0);
#pragma unroll
    for (int p = 0; p < 2; ++p)
      __builtin_amdgcn_global_load_lds(
          (const __attribute__((address_space(1))) void*)(Bg + (size_t)(bn0 + p * 32 + sr) * lb2 + ka),
          (__attribute__((address_space(3))) void*)(Bl + p * 4096), 16, 0, 0);
    __syncthreads();
#pragma unroll
    for (int ks = 0; ks < 2; ++ks) {
      int kb = (kb0 + ks * 64) ^ kx;
      s8v a[2], b[2];
#pragma unroll
      for (int i = 0; i < 2; ++i) a[i] = *(const s8v*)(Ar + i * 2048 + kb);
#pragma unroll
      for (int j = 0; j < 2; ++j) b[j] = *(const s8v*)(Br + j * 2048 + kb);
#pragma unroll
      for (int i = 0; i < 2; ++i)
#pragma unroll
        for (int j = 0; j < 2; ++j)
          acc[i][j] = __builtin_amdgcn_mfma_f32_16x16x32_bf16(a[i], b[j], acc[i][j], 0, 0, 0);
    }
  }
  float* Cfp = Cf + bz * sC;
  unsigned short* Cbp = Cb + bz * sCb;
  const float* Rp = res + bz * sR;
#pragma unroll
  for (int i = 0; i < 2; ++i) {
    int row = bm0 + wm + i * 16 + (lane >> 4) * 4;
#pragma unroll
    for (int r = 0; r < 4; ++r) {
      int rr = row + r;
#pragma unroll
      for (int j = 0; j < 2; ++j) {
        int col = bn0 + wn + j * 16 + (lane & 15);
        float v = acc[i][j][r];
        if (RES) v += Rp[(size_t)rr * ldr + col];
        if (OF32) Cfp[(size_t)rr * ldc + col] = v;
        if (OBF) Cbp[(size_t)rr * ldcb + col] = (unsigned short)f2bf(v);
      }
    }
  }
}

// 64x64 tile transpose: f32 (rows, cols) -> bf16 (cols, rows)
__device__ __forceinline__ void wtrans_tile(const float* src, unsigned short* dst,
                                            int rows, int cols, int c0, int r0) {
  __shared__ float t[64][65];
  int tx = threadIdx.x & 63, ty = threadIdx.x >> 6;
#pragma unroll
  for (int j = 0; j < 16; ++j) {
    int r = j * 4 + ty;
    t[r][tx] = src[(size_t)(r0 + r) * cols + c0 + tx];
  }
  __syncthreads();
#pragma unroll
  for (int j = 0; j < 16; ++j) {
    int n = j * 4 + ty;
    dst[(size_t)(c0 + n) * rows + r0 + tx] = (unsigned short)f2bf(t[tx][n]);
  }
}

__global__ __launch_bounds__(256) void wtrans_k(const float* __restrict__ src,
                                                unsigned short* __restrict__ dst,
                                                int rows, int cols) {
  wtrans_tile(src, dst, rows, cols, blockIdx.x * 64, blockIdx.y * 64);
}

// All 42 H x H weight transposes in one launch. z = l*7 + wi.
__global__ __launch_bounds__(256) void wtrans_all_k(
    const float* __restrict__ w0, const float* __restrict__ w1,
    const float* __restrict__ w2, const float* __restrict__ w3,
    const float* __restrict__ w4, const float* __restrict__ w5,
    const float* __restrict__ w6, unsigned short* __restrict__ dst) {
  int z = blockIdx.z;
  int l = z / 7, wi = z % 7;
  const float* src;
  switch (wi) {
    case 0: src = w0; break;
    case 1: src = w1; break;
    case 2: src = w2; break;
    case 3: src = w3; break;
    case 4: src = w4; break;
    case 5: src = w5; break;
    default: src = w6; break;
  }
  src += (size_t)l * 1024 * 1024;
  unsigned short* d = dst + (size_t)z * 1024 * 1024;
  wtrans_tile(src, d, 1024, 1024, blockIdx.x * 64, blockIdx.y * 64);
}

__global__ __launch_bounds__(256) void convbf_k(const float* __restrict__ src,
                                                unsigned short* __restrict__ dst, int n4) {
  int i = blockIdx.x * 256 + threadIdx.x;
  if (i >= n4) return;
  f4 f = ((const f4*)src)[i];
  s4v v;
  v[0] = f2bf(f[0]); v[1] = f2bf(f[1]); v[2] = f2bf(f[2]); v[3] = f2bf(f[3]);
  ((s4v*)dst)[i] = v;
}

// ---------------------------------------------------------------------------
// Fused softmax + transpose. Sf: (B, Sq, Sk) raw scores f32.
// outT: (B, Sk, Sq) f32 normalized (to d_out). Wb: (B, Sq, Sk) bf16 normalized.
// ---------------------------------------------------------------------------
template<int CAUSAL>
__global__ __launch_bounds__(256) void smt_k(const float* __restrict__ Sf,
                                             float* __restrict__ outT,
                                             unsigned short* __restrict__ Wb) {
  __shared__ float T[16][520];
  int b = blockIdx.y;
  int q0 = blockIdx.x * 16;
  int t = threadIdx.x;
  const float* Sp = Sf + ((size_t)b * 512 + q0) * 512;
#pragma unroll
  for (int j = 0; j < 8; ++j) {
    int idx = t + 256 * j;            // f4 index over 16x128
    int r = idx >> 7, c4 = idx & 127;
    f4 v = *(const f4*)(Sp + (size_t)r * 512 + c4 * 4);
    *(f4*)&T[r][c4 * 4] = v;
  }
  __syncthreads();
  int w = t >> 6, l = t & 63;
  int r = 4 * w + (l >> 4);
  int l16 = l & 15;
  int q = q0 + r;
  const float scale = 0.03125f;
  float v[32];
#pragma unroll
  for (int j = 0; j < 32; ++j) {
    int k = l16 + 16 * j;
    float x = T[r][k] * scale;
    if (CAUSAL && k > q) x += -1.0e7f;
    v[j] = x;
  }
  float m = v[0];
#pragma unroll
  for (int j = 1; j < 32; ++j) m = fmaxf(m, v[j]);
  m = fmaxf(m, __shfl_xor(m, 1)); m = fmaxf(m, __shfl_xor(m, 2));
  m = fmaxf(m, __shfl_xor(m, 4)); m = fmaxf(m, __shfl_xor(m, 8));
  float s = 0.f;
#pragma unroll
  for (int j = 0; j < 32; ++j) { v[j] = __expf(v[j] - m); s += v[j]; }
  s += __shfl_xor(s, 1); s += __shfl_xor(s, 2);
  s += __shfl_xor(s, 4); s += __shfl_xor(s, 8);
  float inv = 1.0f / s;
#pragma unroll
  for (int j = 0; j < 32; ++j) T[r][l16 + 16 * j] = v[j] * inv;
  __syncthreads();
  // transposed f32 write: out[k][q0 + ql]
  float* op = outT + (size_t)b * 512 * 512 + q0;
  int ql = t & 15, kb = t >> 4;
#pragma unroll
  for (int i = 0; i < 32; ++i) {
    int k = kb + 16 * i;
    op[(size_t)k * 512 + ql] = T[ql][k];
  }
  // bf16 (q,k) write
  unsigned short* wp = Wb + ((size_t)b * 512 + q0) * 512;
#pragma unroll
  for (int i = 0; i < 4; ++i) {
    int rr = 4 * w + i;
    const float* row = &T[rr][l * 8];
    s8v o;
#pragma unroll
    for (int j = 0; j < 8; ++j) o[j] = f2bf(row[j]);
    *(s8v*)(wp + (size_t)rr * 512 + l * 8) = o;
  }
}

__global__ __launch_bounds__(256) void embed_pe_k(const int* __restrict__ ids,
                                                  const float* __restrict__ emb,
                                                  float* __restrict__ ctx,
                                                  unsigned short* __restrict__ ctxb) {
  int row = blockIdx.x;  // b*512 + s
  int s = row & 511;
  int t = threadIdx.x;
  int id = ids[row];
  f4 e = *(const f4*)(emb + (size_t)id * 1024 + t * 4);
  int j0 = 2 * t, j1 = 2 * t + 1;
  float fr0 = powf(10000.0f, -2.0f * (float)j0 / 1024.0f);
  float fr1 = powf(10000.0f, -2.0f * (float)j1 / 1024.0f);
  float s0, c0, s1, c1;
  sincosf((float)s * fr0, &s0, &c0);
  sincosf((float)s * fr1, &s1, &c1);
  f4 o;
  o[0] = e[0] + s0; o[1] = e[1] + c0; o[2] = e[2] + s1; o[3] = e[3] + c1;
  *(f4*)(ctx + (size_t)row * 1024 + t * 4) = o;
  s4v ob;
  ob[0] = f2bf(o[0]); ob[1] = f2bf(o[1]); ob[2] = f2bf(o[2]); ob[3] = f2bf(o[3]);
  *(s4v*)(ctxb + (size_t)row * 1024 + t * 4) = ob;
}

extern "C" void kernel_launch(void* const* d_in, const int* in_sizes, int n_in,
                              void* d_out, int out_size, void* d_ws, size_t ws_size,
                              hipStream_t stream) {
  const int B = 8, S = 512, H = 1024, V = 32000, L = 6;
  const int M = B * S;  // 4096

  const int* ids = (const int*)d_in[0];
  const float* ann = (const float*)d_in[1];
  const float* emb = (const float*)d_in[3];
  const float* bq_s = (const float*)d_in[5];
  const float* bk_s = (const float*)d_in[7];
  const float* bv_s = (const float*)d_in[9];
  const float* bq_c = (const float*)d_in[11];
  const float* bk_c = (const float*)d_in[13];
  const float* bv_c = (const float*)d_in[15];
  const float* bm = (const float*)d_in[17];
  const float* Wout = (const float*)d_in[18];
  const float* bout = (const float*)d_in[19];
  float* out = (float*)d_out;

  char* ws = (char*)d_ws;
  if (ws_size < ((size_t)164 << 20)) return;
  float* X0 = (float*)ws;                                             // 16MB residual (in-place)
  unsigned short* Xs0 = (unsigned short*)(ws + ((size_t)16 << 20));   // 8MB bf16 ctx slot 0
  unsigned short* Xs1 = (unsigned short*)(ws + ((size_t)24 << 20));   // 8MB bf16 ctx slot 1
  unsigned short* QKbf = (unsigned short*)(ws + ((size_t)32 << 20));  // 16MB (4096,2048)
  unsigned short* Vtbf = (unsigned short*)(ws + ((size_t)48 << 20));  // 8MB (H,4096)
  float* Sbuf = (float*)(ws + ((size_t)56 << 20));                    // 8MB raw scores f32
  unsigned short* Wbf = (unsigned short*)(ws + ((size_t)64 << 20));   // 4MB softmax bf16
  unsigned short* annbf = (unsigned short*)(ws + ((size_t)68 << 20)); // 8MB
  unsigned short* WT = (unsigned short*)(ws + ((size_t)76 << 20));    // 84MB: 42 x (H,H)
  // scratch inside d_out's logits region (dead until final GEMM):
  unsigned short* KcAll = (unsigned short*)d_out;                     // 48MB: 6 x (4096,H)
  unsigned short* VtcAll = (unsigned short*)((char*)d_out + ((size_t)48 << 20)); // 48MB: 6 x (H,4096)

  size_t enc_off = (size_t)M * V;
  size_t self_off = enc_off + (size_t)L * B * S * S;

  long sQ = (long)S * H;
  long sS = (long)S * S;
  const size_t WSZ = (size_t)H * H;
  const long sW7 = (long)(7 * WSZ);

  embed_pe_k<<<M, 256, 0, stream>>>(ids, emb, X0, Xs0);
  convbf_k<<<(M * H / 4 + 255) / 256, 256, 0, stream>>>(ann, annbf, M * H / 4);
  wtrans_all_k<<<dim3(16, 16, 42), 256, 0, stream>>>(
      (const float*)d_in[4], (const float*)d_in[6], (const float*)d_in[8],
      (const float*)d_in[10], (const float*)d_in[12], (const float*)d_in[14],
      (const float*)d_in[16], WT);
  // All-layer cross K: (l, 4096, H) = ann @ Wk_c[l]
  gemm_bt<1, 0, 0, 0, 1, 0><<<dim3(8, 32, 6), 256, 0, stream>>>(
      annbf, WT + 4 * WSZ, bk_c, nullptr, nullptr, nullptr, KcAll,
      H, H, 0, H, 0, 16, 0, sW7, 0, (long)M * H, 0, H);
  // All-layer cross V^T: (l, H, 4096) = (ann @ Wv_c[l])^T
  gemm_bt<2, 0, 0, 0, 1, 0><<<dim3(32, 8, 6), 256, 0, stream>>>(
      WT + 5 * WSZ, annbf, bv_c, nullptr, nullptr, nullptr, VtcAll,
      H, H, 0, M, 0, 16, sW7, 0, 0, (long)H * M, 0, H);

  unsigned short* Xa = Xs0;
  unsigned short* Xb = Xs1;

  for (int l = 0; l < L; ++l) {
    size_t bo = (size_t)l * H;
    unsigned short* WTl = WT + (size_t)l * 7 * WSZ;

    // ---- self attention ----
    // Q|K = X @ [Wq Wk] : (4096, 2048)
    gemm_bt<3, 0, 0, 0, 1, 0><<<dim3(16, 32), 256, 0, stream>>>(
        Xa, WTl, bq_s + bo, bk_s + bo, nullptr, nullptr, QKbf,
        H, H, 0, 2048, 0, 16, 0, 0, 0, 0, 0, 0);
    // Vt = (X @ Wv)^T : (H, 4096)
    gemm_bt<2, 0, 0, 0, 1, 0><<<dim3(32, 8), 256, 0, stream>>>(
        WTl + 2 * WSZ, Xa, bv_s + bo, nullptr, nullptr, nullptr, Vtbf,
        H, H, 0, M, 0, 16, 0, 0, 0, 0, 0, 0);
    // raw scores (b,q,k) -> Sbuf
    gemm64<0, 1, 0><<<dim3(8, 8, B), 256, 0, stream>>>(
        QKbf, QKbf + 1024, nullptr, Sbuf, nullptr,
        2048, 2048, S, 0, 0, 16, (long)S * 2048, (long)S * 2048, sS, 0, 0);
    smt_k<1><<<dim3(32, B), 256, 0, stream>>>(
        Sbuf, out + self_off + (size_t)l * B * S * S, Wbf);
    // R1 = X0 + W @ V (in-place f32) ; bf16 -> Xb
    gemm64<1, 1, 1><<<dim3(16, 8, B), 256, 0, stream>>>(
        Wbf, Vtbf, X0, X0, Xb,
        S, M, H, H, H, 8, sS, 512, sQ, sQ, sQ);
    // ---- cross attention ----
    gemm_bt<1, 0, 0, 0, 1, 0><<<dim3(8, 32), 256, 0, stream>>>(
        Xb, WTl + 3 * WSZ, bq_c + bo, nullptr, nullptr, nullptr, QKbf,
        H, H, 0, 1024, 0, 16, 0, 0, 0, 0, 0, 0);
    gemm64<0, 1, 0><<<dim3(8, 8, B), 256, 0, stream>>>(
        QKbf, KcAll + (size_t)l * M * H, nullptr, Sbuf, nullptr,
        1024, 1024, S, 0, 0, 16, (long)S * 1024, (long)S * 1024, sS, 0, 0);
    smt_k<0><<<dim3(32, B), 256, 0, stream>>>(
        Sbuf, out + enc_off + (size_t)l * B * S * S, Wbf);
    // R2 = R1 + W @ V (in-place f32) ; bf16 -> Xa
    gemm64<1, 1, 1><<<dim3(16, 8, B), 256, 0, stream>>>(
        Wbf, VtcAll + (size_t)l * H * M, X0, X0, Xa,
        S, M, H, H, H, 8, sS, 512, sQ, sQ, sQ);
    // ctx' = R2 + relu(R2 @ Wm + bm) (in-place f32) ; bf16 -> Xb
    gemm_bt<1, 1, 1, 1, 1, 0><<<dim3(8, 32), 256, 0, stream>>>(
        Xa, WTl + 6 * WSZ, bm + bo, nullptr, X0, X0, Xb,
        H, H, H, H, H, 16, 0, 0, 0, 0, 0, 0);
    unsigned short* tb = Xa; Xa = Xb; Xb = tb;
  }

  // WoutT (V, H) bf16 -> overlay WT region (weights no longer needed)
  wtrans_k<<<dim3(V / 64, H / 64), 256, 0, stream>>>(Wout, WT, H, V);
  // logits = ctx @ Wout + bout   (col-chunk XCD swizzle over 8000 blocks)
  gemm_bt<1, 0, 0, 1, 0, 2><<<dim3(V / 128, M / 128), 256, 0, stream>>>(
      Xa, WT, bout, nullptr, nullptr, out, nullptr,
      H, H, V, 0, 0, 16, 0, 0, 0, 0, 0, 0);
}

// Round 5
// 1751.079 us; speedup vs baseline: 2.1815x; 1.0347x over previous
//
#include <hip/hip_runtime.h>

typedef __attribute__((ext_vector_type(4))) float f4;
typedef __attribute__((ext_vector_type(8))) short s8v;
typedef __attribute__((ext_vector_type(4))) short s4v;

__device__ __forceinline__ short f2bf(float f) {
  union { float f; unsigned int u; } v; v.f = f;
  unsigned int u = v.u;
  unsigned int r = 0x7fffu + ((u >> 16) & 1u);
  return (short)((u + r) >> 16);
}

__device__ __forceinline__ void glds16(const void* g, void* l) {
  __builtin_amdgcn_global_load_lds((const __attribute__((address_space(1))) void*)g,
                                   (__attribute__((address_space(3))) void*)l, 16, 0, 0);
}

// ---------------------------------------------------------------------------
// m97-style bf16 GEMM: C = op(A @ Bt^T).  A:(M,K) bf16 row-major, Bt:(N,K)
// bf16 row-major. 128x128 tile, BK=64, 256 thr = 4 waves of 64x64.
// global_load_lds width-16 staging, both-sides XOR swizzle.
// BIAS: 0 none, 1 per-col, 2 per-row, 3 split per-col (bias | bias2 at 1024).
// SWZ: 0 none, 1 row-chunk XCD swizzle.
// ---------------------------------------------------------------------------
template<int BIAS, int RES, int RELU, int OF32, int OBF, int SWZ>
__global__ __launch_bounds__(256) void gemm_bt(
    const unsigned short* __restrict__ A, const unsigned short* __restrict__ Bt,
    const float* __restrict__ bias, const float* __restrict__ bias2,
    const float* __restrict__ res,
    float* __restrict__ Cf, unsigned short* __restrict__ Cb,
    int lda, int ldb, int ldc, int ldcb, int ldr, int nk,
    long sA, long sB, long sC, long sCb, long sR, long sBias) {
  __shared__ short Alds[128 * 64];
  __shared__ short Blds[128 * 64];
  int tid = threadIdx.x;
  int bx = blockIdx.x, by = blockIdx.y, bz = blockIdx.z;
  if (SWZ == 1) {
    int nx = gridDim.x;
    int nwg = nx * gridDim.y;     // must be %8==0
    int id = by * nx + bx;
    int q = nwg >> 3;
    int nid = (id & 7) * q + (id >> 3);
    bx = nid % nx; by = nid / nx;
  }
  int bm0 = by * 128, bn0 = bx * 128;
  const char* Ag = (const char*)(A + bz * sA);
  const char* Bg = (const char*)(Bt + bz * sB);
  if (BIAS) { bias += bz * sBias; if (BIAS == 3) bias2 += bz * sBias; }
  int w = tid >> 6, lane = tid & 63;
  int sr = tid >> 3;                       // 0..31 staging row within 32-row panel
  int skb = ((tid & 7) ^ (sr & 7)) << 4;   // inverse-swizzled source k-byte
  size_t la2 = (size_t)lda * 2, lb2 = (size_t)ldb * 2;
  char* Al = (char*)Alds + w * 1024;
  char* Bl = (char*)Blds + w * 1024;
  int wm = (w >> 1) * 64, wn = (w & 1) * 64;
  int rb = lane & 15;
  int kx = (lane & 7) << 4;                // read-side swizzle
  int kb0 = (lane >> 4) << 4;
  const char* Ar = (const char*)Alds + (wm + rb) * 128;
  const char* Br = (const char*)Blds + (wn + rb) * 128;
  f4 acc[4][4] = {};
  for (int kt = 0; kt < nk; ++kt) {
    size_t ka = (size_t)kt * 128 + skb;
    __syncthreads();
#pragma unroll
    for (int p = 0; p < 4; ++p)
      glds16(Ag + (size_t)(bm0 + p * 32 + sr) * la2 + ka, Al + p * 4096);
#pragma unroll
    for (int p = 0; p < 4; ++p)
      glds16(Bg + (size_t)(bn0 + p * 32 + sr) * lb2 + ka, Bl + p * 4096);
    __syncthreads();
#pragma unroll
    for (int ks = 0; ks < 2; ++ks) {
      int kb = (kb0 + ks * 64) ^ kx;
      s8v a[4], b[4];
#pragma unroll
      for (int i = 0; i < 4; ++i) a[i] = *(const s8v*)(Ar + i * 2048 + kb);
#pragma unroll
      for (int j = 0; j < 4; ++j) b[j] = *(const s8v*)(Br + j * 2048 + kb);
#pragma unroll
      for (int i = 0; i < 4; ++i)
#pragma unroll
        for (int j = 0; j < 4; ++j)
          acc[i][j] = __builtin_amdgcn_mfma_f32_16x16x32_bf16(a[i], b[j], acc[i][j], 0, 0, 0);
    }
  }
  float* Cfp = Cf + bz * sC;
  unsigned short* Cbp = Cb + bz * sCb;
  const float* Rp = res + bz * sR;
#pragma unroll
  for (int i = 0; i < 4; ++i) {
    int row = bm0 + wm + i * 16 + (lane >> 4) * 4;
#pragma unroll
    for (int r = 0; r < 4; ++r) {
      int rr = row + r;
#pragma unroll
      for (int j = 0; j < 4; ++j) {
        int col = bn0 + wn + j * 16 + (lane & 15);
        float v = acc[i][j][r];
        if (BIAS == 1) v += bias[col];
        if (BIAS == 2) v += bias[rr];
        if (BIAS == 3) v += (col < 1024) ? bias[col] : bias2[col - 1024];
        if (RELU) v = fmaxf(v, 0.f);
        if (RES) v += Rp[(size_t)rr * ldr + col];
        if (OF32) Cfp[(size_t)rr * ldc + col] = v;
        if (OBF) Cbp[(size_t)rr * ldcb + col] = (unsigned short)f2bf(v);
      }
    }
  }
}

// ---------------------------------------------------------------------------
// 64x64-tile variant for small batched GEMMs (scores, PV): 4 waves of 32x32.
// ---------------------------------------------------------------------------
template<int RES, int OF32, int OBF>
__global__ __launch_bounds__(256) void gemm64(
    const unsigned short* __restrict__ A, const unsigned short* __restrict__ Bt,
    const float* __restrict__ res,
    float* __restrict__ Cf, unsigned short* __restrict__ Cb,
    int lda, int ldb, int ldc, int ldcb, int ldr, int nk,
    long sA, long sB, long sC, long sCb, long sR) {
  __shared__ short Alds[64 * 64];
  __shared__ short Blds[64 * 64];
  int tid = threadIdx.x;
  int bx = blockIdx.x, by = blockIdx.y, bz = blockIdx.z;
  int bm0 = by * 64, bn0 = bx * 64;
  const char* Ag = (const char*)(A + bz * sA);
  const char* Bg = (const char*)(Bt + bz * sB);
  int w = tid >> 6, lane = tid & 63;
  int sr = tid >> 3;
  int skb = ((tid & 7) ^ (sr & 7)) << 4;
  size_t la2 = (size_t)lda * 2, lb2 = (size_t)ldb * 2;
  char* Al = (char*)Alds + w * 1024;
  char* Bl = (char*)Blds + w * 1024;
  int wm = (w >> 1) * 32, wn = (w & 1) * 32;
  int rb = lane & 15;
  int kx = (lane & 7) << 4;
  int kb0 = (lane >> 4) << 4;
  const char* Ar = (const char*)Alds + (wm + rb) * 128;
  const char* Br = (const char*)Blds + (wn + rb) * 128;
  f4 acc[2][2] = {};
  for (int kt = 0; kt < nk; ++kt) {
    size_t ka = (size_t)kt * 128 + skb;
    __syncthreads();
#pragma unroll
    for (int p = 0; p < 2; ++p)
      glds16(Ag + (size_t)(bm0 + p * 32 + sr) * la2 + ka, Al + p * 4096);
#pragma unroll
    for (int p = 0; p < 2; ++p)
      glds16(Bg + (size_t)(bn0 + p * 32 + sr) * lb2 + ka, Bl + p * 4096);
    __syncthreads();
#pragma unroll
    for (int ks = 0; ks < 2; ++ks) {
      int kb = (kb0 + ks * 64) ^ kx;
      s8v a[2], b[2];
#pragma unroll
      for (int i = 0; i < 2; ++i) a[i] = *(const s8v*)(Ar + i * 2048 + kb);
#pragma unroll
      for (int j = 0; j < 2; ++j) b[j] = *(const s8v*)(Br + j * 2048 + kb);
#pragma unroll
      for (int i = 0; i < 2; ++i)
#pragma unroll
        for (int j = 0; j < 2; ++j)
          acc[i][j] = __builtin_amdgcn_mfma_f32_16x16x32_bf16(a[i], b[j], acc[i][j], 0, 0, 0);
    }
  }
  float* Cfp = Cf + bz * sC;
  unsigned short* Cbp = Cb + bz * sCb;
  const float* Rp = res + bz * sR;
#pragma unroll
  for (int i = 0; i < 2; ++i) {
    int row = bm0 + wm + i * 16 + (lane >> 4) * 4;
#pragma unroll
    for (int r = 0; r < 4; ++r) {
      int rr = row + r;
#pragma unroll
      for (int j = 0; j < 2; ++j) {
        int col = bn0 + wn + j * 16 + (lane & 15);
        float v = acc[i][j][r];
        if (RES) v += Rp[(size_t)rr * ldr + col];
        if (OF32) Cfp[(size_t)rr * ldc + col] = v;
        if (OBF) Cbp[(size_t)rr * ldcb + col] = (unsigned short)f2bf(v);
      }
    }
  }
}

// ---------------------------------------------------------------------------
// Deep-pipelined logits GEMM: C(4096,32000) = A(4096,1024) @ Bt(32000,1024)^T
// + bias. BM=256 BN=128 BK=64, 512 thr (8 waves, 4Mx2N, 64x64 each).
// 3 LDS buffers (144 KB) -> staging 1.5-2 K-tiles ahead, vmcnt(9) counted
// waits (T3+T4), both-sides XOR swizzle (free 2-way), setprio around MFMA.
// ---------------------------------------------------------------------------
__global__ __launch_bounds__(512) void gemm_logits(
    const unsigned short* __restrict__ A, const unsigned short* __restrict__ Bt,
    const float* __restrict__ bias, float* __restrict__ C) {
  __shared__ __align__(1024) char lds[147456];
  const int ldc = 32000, nk = 16;
  int tid = threadIdx.x;
  int w = tid >> 6, lane = tid & 63;
  // row-chunk XCD swizzle over 4000 blocks (250 x 16)
  int id = blockIdx.y * 250 + blockIdx.x;
  int nid = (id & 7) * 500 + (id >> 3);
  int bx = nid % 250, by = nid / 250;
  int bm0 = by * 256, bn0 = bx * 128;
  const size_t ld2 = 2048;  // K=1024 bf16 row bytes
  const char* Ag = (const char*)A;
  const char* Bg = (const char*)Bt;
  int srow = (w << 3) + (lane >> 3);                       // 0..63, srow&7 == lane>>3
  size_t ska = (size_t)(((lane & 7) ^ (lane >> 3)) << 4);  // inverse-swizzled src kb
  char* bf0 = lds;
  char* bf1 = lds + 49152;
  char* bf2 = lds + 98304;
  int wm = (w >> 1) * 64;   // 4 M groups
  int wn = (w & 1) * 64;    // 2 N groups
  int rsel = lane & 15;
  int kx = (lane & 7) << 4;
  int kb0 = (lane >> 4) << 4;
  f4 acc[4][4] = {};

  // stage half `h` of K-tile kt into buffer: 3 global_load_lds per thread.
  auto stageH = [&](char* buf, int kt, int h) {
    size_t ka = (size_t)kt * 128 + ska;
    if (h == 0) {
      glds16(Ag + (size_t)(bm0 + srow) * ld2 + ka,       buf + w * 1024);
      glds16(Ag + (size_t)(bm0 + 64 + srow) * ld2 + ka,  buf + 8192 + w * 1024);
      glds16(Bg + (size_t)(bn0 + srow) * ld2 + ka,       buf + 32768 + w * 1024);
    } else {
      glds16(Ag + (size_t)(bm0 + 128 + srow) * ld2 + ka, buf + 16384 + w * 1024);
      glds16(Ag + (size_t)(bm0 + 192 + srow) * ld2 + ka, buf + 24576 + w * 1024);
      glds16(Bg + (size_t)(bn0 + 64 + srow) * ld2 + ka,  buf + 40960 + w * 1024);
    }
  };
  // one phase: 8 ds_read_b128 + 16 MFMA over k-slice ks of the buffer.
  auto phase = [&](const char* buf, int ks) {
    const char* Ab = buf + (wm + rsel) * 128;
    const char* Bb = buf + 32768 + (wn + rsel) * 128;
    int kb = (kb0 + ks * 64) ^ kx;
    s8v a0 = *(const s8v*)(Ab + kb);
    s8v a1 = *(const s8v*)(Ab + 2048 + kb);
    s8v a2 = *(const s8v*)(Ab + 4096 + kb);
    s8v a3 = *(const s8v*)(Ab + 6144 + kb);
    s8v q0 = *(const s8v*)(Bb + kb);
    s8v q1 = *(const s8v*)(Bb + 2048 + kb);
    s8v q2 = *(const s8v*)(Bb + 4096 + kb);
    s8v q3 = *(const s8v*)(Bb + 6144 + kb);
    __builtin_amdgcn_s_setprio(1);
    acc[0][0] = __builtin_amdgcn_mfma_f32_16x16x32_bf16(a0, q0, acc[0][0], 0, 0, 0);
    acc[0][1] = __builtin_amdgcn_mfma_f32_16x16x32_bf16(a0, q1, acc[0][1], 0, 0, 0);
    acc[0][2] = __builtin_amdgcn_mfma_f32_16x16x32_bf16(a0, q2, acc[0][2], 0, 0, 0);
    acc[0][3] = __builtin_amdgcn_mfma_f32_16x16x32_bf16(a0, q3, acc[0][3], 0, 0, 0);
    acc[1][0] = __builtin_amdgcn_mfma_f32_16x16x32_bf16(a1, q0, acc[1][0], 0, 0, 0);
    acc[1][1] = __builtin_amdgcn_mfma_f32_16x16x32_bf16(a1, q1, acc[1][1], 0, 0, 0);
    acc[1][2] = __builtin_amdgcn_mfma_f32_16x16x32_bf16(a1, q2, acc[1][2], 0, 0, 0);
    acc[1][3] = __builtin_amdgcn_mfma_f32_16x16x32_bf16(a1, q3, acc[1][3], 0, 0, 0);
    acc[2][0] = __builtin_amdgcn_mfma_f32_16x16x32_bf16(a2, q0, acc[2][0], 0, 0, 0);
    acc[2][1] = __builtin_amdgcn_mfma_f32_16x16x32_bf16(a2, q1, acc[2][1], 0, 0, 0);
    acc[2][2] = __builtin_amdgcn_mfma_f32_16x16x32_bf16(a2, q2, acc[2][2], 0, 0, 0);
    acc[2][3] = __builtin_amdgcn_mfma_f32_16x16x32_bf16(a2, q3, acc[2][3], 0, 0, 0);
    acc[3][0] = __builtin_amdgcn_mfma_f32_16x16x32_bf16(a3, q0, acc[3][0], 0, 0, 0);
    acc[3][1] = __builtin_amdgcn_mfma_f32_16x16x32_bf16(a3, q1, acc[3][1], 0, 0, 0);
    acc[3][2] = __builtin_amdgcn_mfma_f32_16x16x32_bf16(a3, q2, acc[3][2], 0, 0, 0);
    acc[3][3] = __builtin_amdgcn_mfma_f32_16x16x32_bf16(a3, q3, acc[3][3], 0, 0, 0);
    __builtin_amdgcn_s_setprio(0);
  };

  // prologue: stage tiles 0 and 1 (12 loads in flight)
  stageH(bf0, 0, 0); stageH(bf0, 0, 1);
  stageH(bf1, 1, 0); stageH(bf1, 1, 1);

  for (int t = 0; t < nk - 2; ++t) {
    stageH(bf2, t + 2, 0);
    asm volatile("s_waitcnt vmcnt(9)" ::: "memory");  // tile t arrived; 9 newer in flight
    __builtin_amdgcn_s_barrier();
    __builtin_amdgcn_sched_barrier(0);
    phase(bf0, 0);
    __builtin_amdgcn_s_barrier();
    stageH(bf2, t + 2, 1);
    __builtin_amdgcn_s_barrier();
    __builtin_amdgcn_sched_barrier(0);
    phase(bf0, 1);
    __builtin_amdgcn_s_barrier();
    char* tp = bf0; bf0 = bf1; bf1 = bf2; bf2 = tp;
  }
  // tail tile nk-2
  asm volatile("s_waitcnt vmcnt(6)" ::: "memory");
  __builtin_amdgcn_s_barrier();
  __builtin_amdgcn_sched_barrier(0);
  phase(bf0, 0);
  __builtin_amdgcn_s_barrier();
  __builtin_amdgcn_sched_barrier(0);
  phase(bf0, 1);
  __builtin_amdgcn_s_barrier();
  // tail tile nk-1
  asm volatile("s_waitcnt vmcnt(0)" ::: "memory");
  __builtin_amdgcn_s_barrier();
  __builtin_amdgcn_sched_barrier(0);
  phase(bf1, 0);
  phase(bf1, 1);

#pragma unroll
  for (int i = 0; i < 4; ++i) {
    int row = bm0 + wm + i * 16 + (lane >> 4) * 4;
#pragma unroll
    for (int r = 0; r < 4; ++r) {
      float* crow = C + (size_t)(row + r) * ldc + bn0 + wn;
#pragma unroll
      for (int j = 0; j < 4; ++j) {
        int col = j * 16 + rsel;
        crow[col] = acc[i][j][r] + bias[bn0 + wn + col];
      }
    }
  }
}

// 64x64 tile transpose: f32 (rows, cols) -> bf16 (cols, rows)
__device__ __forceinline__ void wtrans_tile(const float* src, unsigned short* dst,
                                            int rows, int cols, int c0, int r0) {
  __shared__ float t[64][65];
  int tx = threadIdx.x & 63, ty = threadIdx.x >> 6;
#pragma unroll
  for (int j = 0; j < 16; ++j) {
    int r = j * 4 + ty;
    t[r][tx] = src[(size_t)(r0 + r) * cols + c0 + tx];
  }
  __syncthreads();
#pragma unroll
  for (int j = 0; j < 16; ++j) {
    int n = j * 4 + ty;
    dst[(size_t)(c0 + n) * rows + r0 + tx] = (unsigned short)f2bf(t[tx][n]);
  }
}

__global__ __launch_bounds__(256) void wtrans_k(const float* __restrict__ src,
                                                unsigned short* __restrict__ dst,
                                                int rows, int cols) {
  wtrans_tile(src, dst, rows, cols, blockIdx.x * 64, blockIdx.y * 64);
}

// All 42 H x H weight transposes in one launch. z = l*7 + wi.
__global__ __launch_bounds__(256) void wtrans_all_k(
    const float* __restrict__ w0, const float* __restrict__ w1,
    const float* __restrict__ w2, const float* __restrict__ w3,
    const float* __restrict__ w4, const float* __restrict__ w5,
    const float* __restrict__ w6, unsigned short* __restrict__ dst) {
  int z = blockIdx.z;
  int l = z / 7, wi = z % 7;
  const float* src;
  switch (wi) {
    case 0: src = w0; break;
    case 1: src = w1; break;
    case 2: src = w2; break;
    case 3: src = w3; break;
    case 4: src = w4; break;
    case 5: src = w5; break;
    default: src = w6; break;
  }
  src += (size_t)l * 1024 * 1024;
  unsigned short* d = dst + (size_t)z * 1024 * 1024;
  wtrans_tile(src, d, 1024, 1024, blockIdx.x * 64, blockIdx.y * 64);
}

__global__ __launch_bounds__(256) void convbf_k(const float* __restrict__ src,
                                                unsigned short* __restrict__ dst, int n4) {
  int i = blockIdx.x * 256 + threadIdx.x;
  if (i >= n4) return;
  f4 f = ((const f4*)src)[i];
  s4v v;
  v[0] = f2bf(f[0]); v[1] = f2bf(f[1]); v[2] = f2bf(f[2]); v[3] = f2bf(f[3]);
  ((s4v*)dst)[i] = v;
}

// ---------------------------------------------------------------------------
// Fused softmax + transpose. Sf: (B, Sq, Sk) raw scores f32.
// outT: (B, Sk, Sq) f32 normalized (to d_out). Wb: (B, Sq, Sk) bf16 normalized.
// ---------------------------------------------------------------------------
template<int CAUSAL>
__global__ __launch_bounds__(256) void smt_k(const float* __restrict__ Sf,
                                             float* __restrict__ outT,
                                             unsigned short* __restrict__ Wb) {
  __shared__ float T[16][520];
  int b = blockIdx.y;
  int q0 = blockIdx.x * 16;
  int t = threadIdx.x;
  const float* Sp = Sf + ((size_t)b * 512 + q0) * 512;
#pragma unroll
  for (int j = 0; j < 8; ++j) {
    int idx = t + 256 * j;            // f4 index over 16x128
    int r = idx >> 7, c4 = idx & 127;
    f4 v = *(const f4*)(Sp + (size_t)r * 512 + c4 * 4);
    *(f4*)&T[r][c4 * 4] = v;
  }
  __syncthreads();
  int w = t >> 6, l = t & 63;
  int r = 4 * w + (l >> 4);
  int l16 = l & 15;
  int q = q0 + r;
  const float scale = 0.03125f;
  float v[32];
#pragma unroll
  for (int j = 0; j < 32; ++j) {
    int k = l16 + 16 * j;
    float x = T[r][k] * scale;
    if (CAUSAL && k > q) x += -1.0e7f;
    v[j] = x;
  }
  float m = v[0];
#pragma unroll
  for (int j = 1; j < 32; ++j) m = fmaxf(m, v[j]);
  m = fmaxf(m, __shfl_xor(m, 1)); m = fmaxf(m, __shfl_xor(m, 2));
  m = fmaxf(m, __shfl_xor(m, 4)); m = fmaxf(m, __shfl_xor(m, 8));
  float s = 0.f;
#pragma unroll
  for (int j = 0; j < 32; ++j) { v[j] = __expf(v[j] - m); s += v[j]; }
  s += __shfl_xor(s, 1); s += __shfl_xor(s, 2);
  s += __shfl_xor(s, 4); s += __shfl_xor(s, 8);
  float inv = 1.0f / s;
#pragma unroll
  for (int j = 0; j < 32; ++j) T[r][l16 + 16 * j] = v[j] * inv;
  __syncthreads();
  // transposed f32 write: out[k][q0 + ql]
  float* op = outT + (size_t)b * 512 * 512 + q0;
  int ql = t & 15, kb = t >> 4;
#pragma unroll
  for (int i = 0; i < 32; ++i) {
    int k = kb + 16 * i;
    op[(size_t)k * 512 + ql] = T[ql][k];
  }
  // bf16 (q,k) write
  unsigned short* wp = Wb + ((size_t)b * 512 + q0) * 512;
#pragma unroll
  for (int i = 0; i < 4; ++i) {
    int rr = 4 * w + i;
    const float* row = &T[rr][l * 8];
    s8v o;
#pragma unroll
    for (int j = 0; j < 8; ++j) o[j] = f2bf(row[j]);
    *(s8v*)(wp + (size_t)rr * 512 + l * 8) = o;
  }
}

__global__ __launch_bounds__(256) void embed_pe_k(const int* __restrict__ ids,
                                                  const float* __restrict__ emb,
                                                  float* __restrict__ ctx,
                                                  unsigned short* __restrict__ ctxb) {
  int row = blockIdx.x;  // b*512 + s
  int s = row & 511;
  int t = threadIdx.x;
  int id = ids[row];
  f4 e = *(const f4*)(emb + (size_t)id * 1024 + t * 4);
  int j0 = 2 * t, j1 = 2 * t + 1;
  float fr0 = powf(10000.0f, -2.0f * (float)j0 / 1024.0f);
  float fr1 = powf(10000.0f, -2.0f * (float)j1 / 1024.0f);
  float s0, c0, s1, c1;
  sincosf((float)s * fr0, &s0, &c0);
  sincosf((float)s * fr1, &s1, &c1);
  f4 o;
  o[0] = e[0] + s0; o[1] = e[1] + c0; o[2] = e[2] + s1; o[3] = e[3] + c1;
  *(f4*)(ctx + (size_t)row * 1024 + t * 4) = o;
  s4v ob;
  ob[0] = f2bf(o[0]); ob[1] = f2bf(o[1]); ob[2] = f2bf(o[2]); ob[3] = f2bf(o[3]);
  *(s4v*)(ctxb + (size_t)row * 1024 + t * 4) = ob;
}

extern "C" void kernel_launch(void* const* d_in, const int* in_sizes, int n_in,
                              void* d_out, int out_size, void* d_ws, size_t ws_size,
                              hipStream_t stream) {
  const int B = 8, S = 512, H = 1024, V = 32000, L = 6;
  const int M = B * S;  // 4096

  const int* ids = (const int*)d_in[0];
  const float* ann = (const float*)d_in[1];
  const float* emb = (const float*)d_in[3];
  const float* bq_s = (const float*)d_in[5];
  const float* bk_s = (const float*)d_in[7];
  const float* bv_s = (const float*)d_in[9];
  const float* bq_c = (const float*)d_in[11];
  const float* bk_c = (const float*)d_in[13];
  const float* bv_c = (const float*)d_in[15];
  const float* bm = (const float*)d_in[17];
  const float* Wout = (const float*)d_in[18];
  const float* bout = (const float*)d_in[19];
  float* out = (float*)d_out;

  char* ws = (char*)d_ws;
  if (ws_size < ((size_t)164 << 20)) return;
  float* X0 = (float*)ws;                                             // 16MB residual (in-place)
  unsigned short* Xs0 = (unsigned short*)(ws + ((size_t)16 << 20));   // 8MB bf16 ctx slot 0
  unsigned short* Xs1 = (unsigned short*)(ws + ((size_t)24 << 20));   // 8MB bf16 ctx slot 1
  unsigned short* QKbf = (unsigned short*)(ws + ((size_t)32 << 20));  // 16MB (4096,2048)
  unsigned short* Vtbf = (unsigned short*)(ws + ((size_t)48 << 20));  // 8MB (H,4096)
  float* Sbuf = (float*)(ws + ((size_t)56 << 20));                    // 8MB raw scores f32
  unsigned short* Wbf = (unsigned short*)(ws + ((size_t)64 << 20));   // 4MB softmax bf16
  unsigned short* annbf = (unsigned short*)(ws + ((size_t)68 << 20)); // 8MB
  unsigned short* WT = (unsigned short*)(ws + ((size_t)76 << 20));    // 84MB: 42 x (H,H)
  // scratch inside d_out's logits region (dead until final GEMM):
  unsigned short* KcAll = (unsigned short*)d_out;                     // 48MB: 6 x (4096,H)
  unsigned short* VtcAll = (unsigned short*)((char*)d_out + ((size_t)48 << 20)); // 48MB: 6 x (H,4096)

  size_t enc_off = (size_t)M * V;
  size_t self_off = enc_off + (size_t)L * B * S * S;

  long sQ = (long)S * H;
  long sS = (long)S * S;
  const size_t WSZ = (size_t)H * H;
  const long sW7 = (long)(7 * WSZ);

  embed_pe_k<<<M, 256, 0, stream>>>(ids, emb, X0, Xs0);
  convbf_k<<<(M * H / 4 + 255) / 256, 256, 0, stream>>>(ann, annbf, M * H / 4);
  wtrans_all_k<<<dim3(16, 16, 42), 256, 0, stream>>>(
      (const float*)d_in[4], (const float*)d_in[6], (const float*)d_in[8],
      (const float*)d_in[10], (const float*)d_in[12], (const float*)d_in[14],
      (const float*)d_in[16], WT);
  // All-layer cross K: (l, 4096, H) = ann @ Wk_c[l]
  gemm_bt<1, 0, 0, 0, 1, 0><<<dim3(8, 32, 6), 256, 0, stream>>>(
      annbf, WT + 4 * WSZ, bk_c, nullptr, nullptr, nullptr, KcAll,
      H, H, 0, H, 0, 16, 0, sW7, 0, (long)M * H, 0, H);
  // All-layer cross V^T: (l, H, 4096) = (ann @ Wv_c[l])^T
  gemm_bt<2, 0, 0, 0, 1, 0><<<dim3(32, 8, 6), 256, 0, stream>>>(
      WT + 5 * WSZ, annbf, bv_c, nullptr, nullptr, nullptr, VtcAll,
      H, H, 0, M, 0, 16, sW7, 0, 0, (long)H * M, 0, H);

  unsigned short* Xa = Xs0;
  unsigned short* Xb = Xs1;

  for (int l = 0; l < L; ++l) {
    size_t bo = (size_t)l * H;
    unsigned short* WTl = WT + (size_t)l * 7 * WSZ;

    // ---- self attention ----
    // Q|K = X @ [Wq Wk] : (4096, 2048)
    gemm_bt<3, 0, 0, 0, 1, 0><<<dim3(16, 32), 256, 0, stream>>>(
        Xa, WTl, bq_s + bo, bk_s + bo, nullptr, nullptr, QKbf,
        H, H, 0, 2048, 0, 16, 0, 0, 0, 0, 0, 0);
    // Vt = (X @ Wv)^T : (H, 4096)
    gemm_bt<2, 0, 0, 0, 1, 0><<<dim3(32, 8), 256, 0, stream>>>(
        WTl + 2 * WSZ, Xa, bv_s + bo, nullptr, nullptr, nullptr, Vtbf,
        H, H, 0, M, 0, 16, 0, 0, 0, 0, 0, 0);
    // raw scores (b,q,k) -> Sbuf
    gemm64<0, 1, 0><<<dim3(8, 8, B), 256, 0, stream>>>(
        QKbf, QKbf + 1024, nullptr, Sbuf, nullptr,
        2048, 2048, S, 0, 0, 16, (long)S * 2048, (long)S * 2048, sS, 0, 0);
    smt_k<1><<<dim3(32, B), 256, 0, stream>>>(
        Sbuf, out + self_off + (size_t)l * B * S * S, Wbf);
    // R1 = X0 + W @ V (in-place f32) ; bf16 -> Xb
    gemm64<1, 1, 1><<<dim3(16, 8, B), 256, 0, stream>>>(
        Wbf, Vtbf, X0, X0, Xb,
        S, M, H, H, H, 8, sS, 512, sQ, sQ, sQ);
    // ---- cross attention ----
    gemm_bt<1, 0, 0, 0, 1, 0><<<dim3(8, 32), 256, 0, stream>>>(
        Xb, WTl + 3 * WSZ, bq_c + bo, nullptr, nullptr, nullptr, QKbf,
        H, H, 0, 1024, 0, 16, 0, 0, 0, 0, 0, 0);
    gemm64<0, 1, 0><<<dim3(8, 8, B), 256, 0, stream>>>(
        QKbf, KcAll + (size_t)l * M * H, nullptr, Sbuf, nullptr,
        1024, 1024, S, 0, 0, 16, (long)S * 1024, (long)S * 1024, sS, 0, 0);
    smt_k<0><<<dim3(32, B), 256, 0, stream>>>(
        Sbuf, out + enc_off + (size_t)l * B * S * S, Wbf);
    // R2 = R1 + W @ V (in-place f32) ; bf16 -> Xa
    gemm64<1, 1, 1><<<dim3(16, 8, B), 256, 0, stream>>>(
        Wbf, VtcAll + (size_t)l * H * M, X0, X0, Xa,
        S, M, H, H, H, 8, sS, 512, sQ, sQ, sQ);
    // ctx' = R2 + relu(R2 @ Wm + bm) (in-place f32) ; bf16 -> Xb
    gemm_bt<1, 1, 1, 1, 1, 0><<<dim3(8, 32), 256, 0, stream>>>(
        Xa, WTl + 6 * WSZ, bm + bo, nullptr, X0, X0, Xb,
        H, H, H, H, H, 16, 0, 0, 0, 0, 0, 0);
    unsigned short* tb = Xa; Xa = Xb; Xb = tb;
  }

  // WoutT (V, H) bf16 -> overlay WT region (weights no longer needed)
  wtrans_k<<<dim3(V / 64, H / 64), 256, 0, stream>>>(Wout, WT, H, V);
  // logits = ctx @ Wout + bout   (deep-pipelined 256x128 kernel)
  gemm_logits<<<dim3(250, 16), 512, 0, stream>>>(Xa, WT, bout, out);
}